// Round 24
// baseline (332.203 us; speedup 1.0000x reference)
//
#include <hip/hip_runtime.h>
#include <hip/hip_bf16.h>
#include <math.h>

typedef _Float16 f16x8 __attribute__((ext_vector_type(8)));
typedef float f32x4 __attribute__((ext_vector_type(4)));
typedef unsigned int u32;
typedef unsigned short u16;

#define NROWS 131072
#define DDIM 224
#define HREAL 400
#define HP 416          // padded hidden dim (13*32)
#define ROWS 32         // rows per block
#define PROW 832        // 52 units of 16B; XOR-unit swizzle (unit ^ (row&3))
#define PLANE 26624     // one plane: 32 * 832
#define LDS_TOTAL 53248 // plane A + plane B; 3 blocks/CU

// ---- workspace layout (bytes); weights single-f16 fragment-linear ----
#define OFF_W1    0          // [26nb][7ks][4g][16l][8] u16 = 186368 B
#define OFF_W2    186368     // [26][13][4][16][8] = 346112 B
#define OFF_W5    532480     // 346112 B
#define OFF_W6    878592     // [14][13][4][16][8] = 186368 B
#define OFF_W3    1064960    // [1][13][4][16][8] = 13312 B  (We3 as B-frag, N=16 cols<4 real)
#define OFF_W4    1078272    // [26][1][4][16][8] = 26624 B  (Wd1 as B-frag, K=32 k<4 real)
#define OFF_C     1104896    // f32 scalar ||d||
#define OFF_MSEP  1104912    // f32 [4096]
#define OFF_DEFEN 1121296    // f32 [131072]
#define OFF_CAND  1645584    // f32 [1280]
// total 1650704 bytes

__device__ __forceinline__ u16 f2h(float v) {
  union { _Float16 h; u16 u; } c;
  c.h = (_Float16)v;
  return c.u;
}

// single-f16 fragment packing: u16 index i -> (nb, ks, g, l15, e)
__device__ __forceinline__ void pack8(int i, int NKS, int KREAL, int NREAL, int NLD,
                                      const float* __restrict__ W,
                                      u16* __restrict__ Wo) {
  const int e = i & 7, l15 = (i >> 3) & 15, g = (i >> 7) & 3;
  const int rest = i >> 9;
  const int ks = rest % NKS, nb = rest / NKS;
  const int n = nb * 16 + l15, k = ks * 32 + g * 8 + e;
  const float w = (n < NREAL && k < KREAL) ? W[k * NLD + n] : 0.f;
  Wo[i] = f2h(w);
}

__global__ void k_prep(const float* __restrict__ We1, const float* __restrict__ We2,
                       const float* __restrict__ Wd2, const float* __restrict__ Wd3,
                       const float* __restrict__ We3, const float* __restrict__ Wd1,
                       const float* __restrict__ dvec,
                       u16* __restrict__ W1, u16* __restrict__ W2,
                       u16* __restrict__ W5, u16* __restrict__ W6,
                       u16* __restrict__ W3, u16* __restrict__ W4,
                       float* __restrict__ Cout) {
  const int t = blockIdx.x * 256 + threadIdx.x;
  const int NT = gridDim.x * 256;
  for (int i = t; i < 26 * 7 * 512;  i += NT) pack8(i, 7,  DDIM,  HREAL, HREAL, We1, W1);
  for (int i = t; i < 26 * 13 * 512; i += NT) pack8(i, 13, HREAL, HREAL, HREAL, We2, W2);
  for (int i = t; i < 26 * 13 * 512; i += NT) pack8(i, 13, HREAL, HREAL, HREAL, Wd2, W5);
  for (int i = t; i < 14 * 13 * 512; i += NT) pack8(i, 13, HREAL, DDIM,  DDIM,  Wd3, W6);
  for (int i = t; i < 1 * 13 * 512;  i += NT) pack8(i, 13, HREAL, 4,     4,     We3, W3);
  for (int i = t; i < 26 * 1 * 512;  i += NT) pack8(i, 1,  4,     HREAL, HREAL, Wd1, W4);
  if (blockIdx.x == 0) {
    float s = 0.f;
    for (int i = threadIdx.x; i < DDIM; i += 256) { float v = dvec[i]; s += v * v; }
#pragma unroll
    for (int off = 1; off < 64; off <<= 1) s += __shfl_xor(s, off);
    __shared__ float cs[4];
    if ((threadIdx.x & 63) == 0) cs[threadIdx.x >> 6] = s;
    __syncthreads();
    if (threadIdx.x == 0) Cout[0] = sqrtf(cs[0] + cs[1] + cs[2] + cs[3]);
  }
}

// ------- GEMM chunk: 2 M-frags x NFW N-frags, f16 single-W, 2-deep prefetch -------
// XOR-unit swizzle folds into the per-thread base (g' = g ^ (l15&3)); k-loop A
// addresses are base + ks*64 compile-time offsets -> zero per-k-step VALU.
template <int NKS, int NFW>
__device__ __forceinline__ void gemmN(const char* ip, const u16* __restrict__ W,
                                      int nb0, int l15, int g, f32x4 (&acc)[2][NFW]) {
  const int lof = (g << 7) + (l15 << 3);
  const int gs = g ^ (l15 & 3);                 // swizzled unit low bits
  const char* a0b = ip + l15 * PROW + gs * 16;
  const char* a1b = a0b + 16 * PROW;            // (l15+16)&3 == l15&3 -> same gs
  const u16* wp[NFW];
#pragma unroll
  for (int nf = 0; nf < NFW; ++nf)
    wp[nf] = W + ((((size_t)(nb0 + nf) * NKS) << 9) + lof);
  f16x8 b[NFW][3];
#pragma unroll
  for (int nf = 0; nf < NFW; ++nf) b[nf][0] = *(const f16x8*)wp[nf];
  if (NKS > 1) {
#pragma unroll
    for (int nf = 0; nf < NFW; ++nf) b[nf][1] = *(const f16x8*)(wp[nf] + 512);
  }
#pragma unroll
  for (int ks = 0; ks < NKS; ++ks) {
    const int cur = ks % 3;
    if (ks + 2 < NKS) {
      const int nxt = (ks + 2) % 3;
#pragma unroll
      for (int nf = 0; nf < NFW; ++nf)
        b[nf][nxt] = *(const f16x8*)(wp[nf] + (size_t)(ks + 2) * 512);
    }
    const f16x8 a0 = *(const f16x8*)(a0b + ks * 64);
    const f16x8 a1 = *(const f16x8*)(a1b + ks * 64);
    __builtin_amdgcn_s_setprio(1);
#pragma unroll
    for (int nf = 0; nf < NFW; ++nf) {
      acc[0][nf] = __builtin_amdgcn_mfma_f32_16x16x32_f16(a0, b[nf][cur], acc[0][nf], 0, 0, 0);
      acc[1][nf] = __builtin_amdgcn_mfma_f32_16x16x32_f16(a1, b[nf][cur], acc[1][nf], 0, 0, 0);
    }
    __builtin_amdgcn_s_setprio(0);
  }
}

// ---------------- activation epilogue: bias + lrelu -> OUT plane (f16, XOR-swz) -----
template <int NFW>
__device__ __forceinline__ void epiN(f32x4 (&acc)[2][NFW], const float* __restrict__ bias,
                                     int nb0, char* op, int l15, int g) {
#pragma unroll
  for (int nf = 0; nf < NFW; ++nf) {
    const int col = (nb0 + nf) * 16 + l15;
    const float bv = (col < HREAL) ? bias[col] : 0.f;
    const int cu = col >> 3;            // 16B unit
    const int crem = (col & 7) * 2;     // byte within unit
#pragma unroll
    for (int mf = 0; mf < 2; ++mf) {
#pragma unroll
      for (int j = 0; j < 4; ++j) {
        const int row = mf * 16 + g * 4 + j;
        float v = acc[mf][nf][j] + bv;
        v = fmaxf(v, 0.1f * v);
        *(u16*)(op + row * PROW + ((cu ^ (row & 3)) << 4) + crem) = f2h(v);
      }
    }
  }
}

// ---- one hidden layer: 7 chunks {4,4,4,4,4,4,2} round-robin over 4 waves ----
template <int NKS>
__device__ __forceinline__ void layerN(const char* ip, char* op,
                                       const u16* __restrict__ W,
                                       const float* __restrict__ bias,
                                       int wid, int l15, int g) {
  for (int ci = wid; ci < 7; ci += 4) {
    const int nb0 = 4 * ci;
    if (ci == 6) {
      f32x4 acc[2][2] = {};
      gemmN<NKS, 2>(ip, W, nb0, l15, g, acc);
      epiN<2>(acc, bias, nb0, op, l15, g);
    } else {
      f32x4 acc[2][4] = {};
      gemmN<NKS, 4>(ip, W, nb0, l15, g, acc);
      epiN<4>(acc, bias, nb0, op, l15, g);
    }
  }
}

// ---- L6 chunk: gemm + tanh + y-store + fused partial A/B/M ----
template <int NFW>
__device__ __forceinline__ void l6N(const char* ip, const u16* __restrict__ W6,
                                    const float* __restrict__ bd3,
                                    const float* __restrict__ dvec,
                                    const float* __restrict__ xin,
                                    float* __restrict__ y_out,
                                    size_t row0, int nb0, int l15, int g,
                                    float (&pA)[2][4], float (&pB)[2][4], float (&pM)[2][4]) {
  f32x4 acc[2][NFW] = {};
  gemmN<13, NFW>(ip, W6, nb0, l15, g, acc);
#pragma unroll
  for (int mf = 0; mf < 2; ++mf) {
#pragma unroll
    for (int j = 0; j < 4; ++j) {
      const size_t grow = row0 + mf * 16 + g * 4 + j;
#pragma unroll
      for (int nf = 0; nf < NFW; ++nf) {
        const int col = (nb0 + nf) * 16 + l15;
        const float v = acc[mf][nf][j] + bd3[col];
        const float e = __expf(2.f * v);
        const float y = 1.f - 2.f * __builtin_amdgcn_rcpf(e + 1.f);
        y_out[grow * DDIM + col] = y;
        pA[mf][j] = fmaf(y, dvec[col], pA[mf][j]);
        pB[mf][j] = fmaf(y, y, pB[mf][j]);
        const float df = y - xin[grow * DDIM + col];
        pM[mf][j] = fmaf(df, df, pM[mf][j]);
      }
    }
  }
}

// ---------------- main fused kernel: 32 rows per block, 256 threads ----------------
// Ping-pong planes; L3/L4 are MFMA too (z as a K=32 A-fragment in the plane).
__global__ __launch_bounds__(256, 3) void k_main(
    const float* __restrict__ xin, const float* __restrict__ dvec,
    const float* __restrict__ be1, const float* __restrict__ be2, const float* __restrict__ be3,
    const float* __restrict__ bd1, const float* __restrict__ bd2, const float* __restrict__ bd3,
    const u16* __restrict__ W1, const u16* __restrict__ W2,
    const u16* __restrict__ W5, const u16* __restrict__ W6,
    const u16* __restrict__ W3, const u16* __restrict__ W4,
    const float* __restrict__ Cptr,
    float* __restrict__ y_out, float* __restrict__ z_out,
    float* __restrict__ defen, float* __restrict__ msep) {
  extern __shared__ __align__(16) char lds[];
  char* pa = lds;              // plane A
  char* pb = lds + PLANE;      // plane B

  const int tid = threadIdx.x;
  const int lane = tid & 63;
  const int wid = tid >> 6;       // 0..3
  const int l15 = lane & 15;
  const int g = lane >> 4;        // 0..3
  const size_t row0 = (size_t)blockIdx.x * ROWS;

  // ---- stage x -> plane A (f16, XOR-swz units) ----
#pragma unroll
  for (int i = 0; i < 7; ++i) {
    const int f = i * 256 + tid;                 // 32 rows * 56 float4 = 1792
    const int r = f / 56, c4 = f - r * 56;
    const float4 v = *(const float4*)(xin + (row0 + r) * DDIM + c4 * 4);
    const float vv[4] = {v.x, v.y, v.z, v.w};
    ushort4 hh;
    u16* hw = (u16*)&hh;
#pragma unroll
    for (int w = 0; w < 4; ++w) hw[w] = f2h(vv[w]);
    *(ushort4*)(pa + r * PROW + (((c4 >> 1) ^ (r & 3)) << 4) + (c4 & 1) * 8) = hh;
  }
  __syncthreads();

  // ---- L1: x(A) -> h1(B) ----
  layerN<7>(pa, pb, W1, be1, wid, l15, g);
  __syncthreads();

  // ---- L2: h1(B) -> h2(A) ----
  layerN<13>(pb, pa, W2, be2, wid, l15, g);
  __syncthreads();

  // ---- L3 (MFMA): z = h2(A) @ We3 + be3; wave 0 only ----
  // Output z scattered into plane B as a ready A-fragment (K=32, k<4 real).
  if (wid == 0) {
    f32x4 acc3[2][1] = {};
    gemmN<13, 1>(pa, W3, 0, l15, g, acc3);
    float zv[2][4];
#pragma unroll
    for (int mf = 0; mf < 2; ++mf) {
#pragma unroll
      for (int j = 0; j < 4; ++j) {
        const float s = acc3[mf][0][j] + ((l15 < 4) ? be3[l15] : 0.f);
        zv[mf][j] = s;
        if (l15 < 4) z_out[(row0 + mf * 16 + g * 4 + j) * 4 + l15] = s;
      }
    }
    // pack z (k=0..3) into unit 0; zero units 1..3 (k=8..31) of each row
#pragma unroll
    for (int mf = 0; mf < 2; ++mf) {
#pragma unroll
      for (int j = 0; j < 4; ++j) {
        const float z0 = __shfl(zv[mf][j], (lane & ~15) + 0);
        const float z1 = __shfl(zv[mf][j], (lane & ~15) + 1);
        const float z2 = __shfl(zv[mf][j], (lane & ~15) + 2);
        const float z3 = __shfl(zv[mf][j], (lane & ~15) + 3);
        if (l15 < 4) {
          const int r = mf * 16 + g * 4 + j;
          uint4 zq = {0u, 0u, 0u, 0u};
          if (l15 == 0) {
            zq.x = (u32)f2h(z0) | ((u32)f2h(z1) << 16);
            zq.y = (u32)f2h(z2) | ((u32)f2h(z3) << 16);
          }
          *(uint4*)(pb + r * PROW + ((l15 ^ (r & 3)) << 4)) = zq;
        }
      }
    }
  }
  __syncthreads();

  // ---- L4 (MFMA): g1 = lrelu(z(B) @ Wd1 + bd1) -> plane A ----
  layerN<1>(pb, pa, W4, bd1, wid, l15, g);
  __syncthreads();

  // ---- L5: g2 = lrelu(g1(A) @ Wd2 + bd2) -> plane B ----
  layerN<13>(pa, pb, W5, bd2, wid, l15, g);
  __syncthreads();                 // A now free (red overlay), B holds g2

  // ---- L6: y = tanh(g2(B) @ Wd3 + bd3) + fused reductions ----
  // 14 nb in 4 chunks {4,4,4,2}; wave w takes chunk w.
  {
    float pA[2][4] = {}, pB[2][4] = {}, pM[2][4] = {};
    if (wid < 3) l6N<4>(pb, W6, bd3, dvec, xin, y_out, row0, 4 * wid, l15, g, pA, pB, pM);
    else         l6N<2>(pb, W6, bd3, dvec, xin, y_out, row0, 12,      l15, g, pA, pB, pM);
    float* red = (float*)pa;       // [32 rows][4 waves][4]
#pragma unroll
    for (int mf = 0; mf < 2; ++mf) {
#pragma unroll
      for (int j = 0; j < 4; ++j) {
        float a = pA[mf][j], b = pB[mf][j], m = pM[mf][j];
#pragma unroll
        for (int off = 1; off < 16; off <<= 1) {
          a += __shfl_xor(a, off);
          b += __shfl_xor(b, off);
          m += __shfl_xor(m, off);
        }
        if (l15 == 0) {
          const int lrow = mf * 16 + g * 4 + j;
          red[(lrow * 4 + wid) * 4 + 0] = a;
          red[(lrow * 4 + wid) * 4 + 1] = b;
          red[(lrow * 4 + wid) * 4 + 2] = m;
        }
      }
    }
  }
  __syncthreads();

  if (tid < 32) {
    const float Cn = Cptr[0];
    const float* red = (const float*)pa;
    float A = 0.f, B2 = 0.f, M = 0.f;
#pragma unroll
    for (int w = 0; w < 4; ++w) {
      A  += red[(tid * 4 + w) * 4 + 0];
      B2 += red[(tid * 4 + w) * 4 + 1];
      M  += red[(tid * 4 + w) * 4 + 2];
    }
    defen[row0 + tid] = A / (sqrtf(B2) * Cn + 1e-5f);
#pragma unroll
    for (int off = 1; off < 32; off <<= 1) M += __shfl_xor(M, off);
    if (tid == 0) msep[blockIdx.x] = M;
  }
}

// ---------------- top-k stage A: 64 blocks, per-block top-20 of 2048 ----------------
__global__ void k_topk_a(const float* __restrict__ defen, float* __restrict__ cand) {
  __shared__ float vals[2048];
  __shared__ float wv[4];
  __shared__ int wi[4];
  const int tid = threadIdx.x;
  const int base = blockIdx.x * 2048;
  for (int i = tid; i < 2048; i += 256) vals[i] = defen[base + i];
  __syncthreads();
  for (int it = 0; it < 20; ++it) {
    float mv = -1e30f; int mi = 1 << 30;
    for (int i = tid; i < 2048; i += 256) {
      float v = vals[i];
      if (v > mv) { mv = v; mi = i; }
    }
#pragma unroll
    for (int off = 1; off < 64; off <<= 1) {
      float ov = __shfl_xor(mv, off); int oi = __shfl_xor(mi, off);
      if (ov > mv || (ov == mv && oi < mi)) { mv = ov; mi = oi; }
    }
    if ((tid & 63) == 0) { wv[tid >> 6] = mv; wi[tid >> 6] = mi; }
    __syncthreads();
    if (tid == 0) {
      float bv = wv[0]; int bi = wi[0];
      for (int q = 1; q < 4; ++q)
        if (wv[q] > bv || (wv[q] == bv && wi[q] < bi)) { bv = wv[q]; bi = wi[q]; }
      cand[blockIdx.x * 20 + it] = bv;
      vals[bi] = -1e30f;
    }
    __syncthreads();
  }
}

// ---------------- top-k stage B: final top-20 of 1280 + R_loss ----------------
__global__ void k_topk_b(const float* __restrict__ cand, const float* __restrict__ msep,
                         float* __restrict__ rloss) {
  __shared__ float vals[1280];
  __shared__ float wv[4];
  __shared__ int wi[4];
  __shared__ float msum[4];
  const int tid = threadIdx.x;
  for (int i = tid; i < 1280; i += 256) vals[i] = cand[i];
  float ms = 0.f;
  for (int i = tid; i < 4096; i += 256) ms += msep[i];
#pragma unroll
  for (int off = 1; off < 64; off <<= 1) ms += __shfl_xor(ms, off);
  if ((tid & 63) == 0) msum[tid >> 6] = ms;
  __syncthreads();
  float sam = 0.f;
  for (int it = 0; it < 20; ++it) {
    float mv = -1e30f; int mi = 1 << 30;
    for (int i = tid; i < 1280; i += 256) {
      float v = vals[i];
      if (v > mv) { mv = v; mi = i; }
    }
#pragma unroll
    for (int off = 1; off < 64; off <<= 1) {
      float ov = __shfl_xor(mv, off); int oi = __shfl_xor(mi, off);
      if (ov > mv || (ov == mv && oi < mi)) { mv = ov; mi = oi; }
    }
    if ((tid & 63) == 0) { wv[tid >> 6] = mv; wi[tid >> 6] = mi; }
    __syncthreads();
    if (tid == 0) {
      float bv = wv[0]; int bi = wi[0];
      for (int q = 1; q < 4; ++q)
        if (wv[q] > bv || (wv[q] == bv && wi[q] < bi)) { bv = wv[q]; bi = wi[q]; }
      sam += bv;
      vals[bi] = -1e30f;
    }
    __syncthreads();
  }
  if (tid == 0) {
    float mse = (msum[0] + msum[1] + msum[2] + msum[3]) / 29360128.f;  // N*D
    rloss[0] = mse + 0.1f * sam;
  }
}

extern "C" void kernel_launch(void* const* d_in, const int* in_sizes, int n_in,
                              void* d_out, int out_size, void* d_ws, size_t ws_size,
                              hipStream_t stream) {
  const float* x    = (const float*)d_in[0];
  const float* dinp = (const float*)d_in[1];
  const float* We1  = (const float*)d_in[2];
  const float* be1  = (const float*)d_in[3];
  const float* We2  = (const float*)d_in[4];
  const float* be2  = (const float*)d_in[5];
  const float* We3  = (const float*)d_in[6];
  const float* be3  = (const float*)d_in[7];
  const float* Wd1  = (const float*)d_in[8];
  const float* bd1  = (const float*)d_in[9];
  const float* Wd2  = (const float*)d_in[10];
  const float* bd2  = (const float*)d_in[11];
  const float* Wd3  = (const float*)d_in[12];
  const float* bd3  = (const float*)d_in[13];

  float* y_out = (float*)d_out;
  float* z_out = y_out + (size_t)NROWS * DDIM;
  float* r_out = z_out + (size_t)NROWS * 4;

  char* ws = (char*)d_ws;
  u16* W1 = (u16*)(ws + OFF_W1);
  u16* W2 = (u16*)(ws + OFF_W2);
  u16* W5 = (u16*)(ws + OFF_W5);
  u16* W6 = (u16*)(ws + OFF_W6);
  u16* W3 = (u16*)(ws + OFF_W3);
  u16* W4 = (u16*)(ws + OFF_W4);
  float* Cf    = (float*)(ws + OFF_C);
  float* msep  = (float*)(ws + OFF_MSEP);
  float* defen = (float*)(ws + OFF_DEFEN);
  float* cand  = (float*)(ws + OFF_CAND);

  (void)hipFuncSetAttribute((const void*)k_main, hipFuncAttributeMaxDynamicSharedMemorySize, LDS_TOTAL);

  k_prep<<<dim3(256), dim3(256), 0, stream>>>(We1, We2, Wd2, Wd3, We3, Wd1, dinp,
                                              W1, W2, W5, W6, W3, W4, Cf);
  k_main<<<dim3(4096), dim3(256), LDS_TOTAL, stream>>>(x, dinp, be1, be2, be3, bd1, bd2, bd3,
                                                       W1, W2, W5, W6, W3, W4,
                                                       Cf, y_out, z_out, defen, msep);
  k_topk_a<<<dim3(64), dim3(256), 0, stream>>>(defen, cand);
  k_topk_b<<<dim3(1), dim3(256), 0, stream>>>(cand, msep, r_out);
}

// Round 25
// 332.062 us; speedup vs baseline: 1.0004x; 1.0004x over previous
//
#include <hip/hip_runtime.h>
#include <hip/hip_bf16.h>
#include <math.h>

typedef _Float16 f16x8 __attribute__((ext_vector_type(8)));
typedef float f32x4 __attribute__((ext_vector_type(4)));
typedef unsigned int u32;
typedef unsigned short u16;

#define NROWS 131072
#define DDIM 224
#define HREAL 400
#define HP 416          // padded hidden dim (13*32)
#define ROWS 32         // rows per block
#define PROW 832        // 52 units of 16B; XOR-unit swizzle (unit ^ (row&3))
#define PLANE 26624     // one plane: 32 * 832
#define LDS_TOTAL 53248 // plane A + plane B; 3 blocks/CU

// ---- workspace layout (bytes); weights single-f16 fragment-linear ----
#define OFF_W1    0          // [26nb][7ks][4g][16l][8] u16 = 186368 B
#define OFF_W2    186368     // [26][13][4][16][8] = 346112 B
#define OFF_W5    532480     // 346112 B
#define OFF_W6    878592     // [14][13][4][16][8] = 186368 B
#define OFF_W3    1064960    // [1][13][4][16][8] = 13312 B  (We3 as B-frag, N=16 cols<4 real)
#define OFF_W4    1078272    // [26][1][4][16][8] = 26624 B  (Wd1 as B-frag, K=32 k<4 real)
#define OFF_C     1104896    // f32 scalar ||d||
#define OFF_MSEP  1104912    // f32 [4096]
#define OFF_DEFEN 1121296    // f32 [131072]
#define OFF_CAND  1645584    // f32 [1280]
// total 1650704 bytes

__device__ __forceinline__ u16 f2h(float v) {
  union { _Float16 h; u16 u; } c;
  c.h = (_Float16)v;
  return c.u;
}

// single-f16 fragment packing: u16 index i -> (nb, ks, g, l15, e)
__device__ __forceinline__ void pack8(int i, int NKS, int KREAL, int NREAL, int NLD,
                                      const float* __restrict__ W,
                                      u16* __restrict__ Wo) {
  const int e = i & 7, l15 = (i >> 3) & 15, g = (i >> 7) & 3;
  const int rest = i >> 9;
  const int ks = rest % NKS, nb = rest / NKS;
  const int n = nb * 16 + l15, k = ks * 32 + g * 8 + e;
  const float w = (n < NREAL && k < KREAL) ? W[k * NLD + n] : 0.f;
  Wo[i] = f2h(w);
}

__global__ void k_prep(const float* __restrict__ We1, const float* __restrict__ We2,
                       const float* __restrict__ Wd2, const float* __restrict__ Wd3,
                       const float* __restrict__ We3, const float* __restrict__ Wd1,
                       const float* __restrict__ dvec,
                       u16* __restrict__ W1, u16* __restrict__ W2,
                       u16* __restrict__ W5, u16* __restrict__ W6,
                       u16* __restrict__ W3, u16* __restrict__ W4,
                       float* __restrict__ Cout) {
  const int t = blockIdx.x * 256 + threadIdx.x;
  const int NT = gridDim.x * 256;
  for (int i = t; i < 26 * 7 * 512;  i += NT) pack8(i, 7,  DDIM,  HREAL, HREAL, We1, W1);
  for (int i = t; i < 26 * 13 * 512; i += NT) pack8(i, 13, HREAL, HREAL, HREAL, We2, W2);
  for (int i = t; i < 26 * 13 * 512; i += NT) pack8(i, 13, HREAL, HREAL, HREAL, Wd2, W5);
  for (int i = t; i < 14 * 13 * 512; i += NT) pack8(i, 13, HREAL, DDIM,  DDIM,  Wd3, W6);
  for (int i = t; i < 1 * 13 * 512;  i += NT) pack8(i, 13, HREAL, 4,     4,     We3, W3);
  for (int i = t; i < 26 * 1 * 512;  i += NT) pack8(i, 1,  4,     HREAL, HREAL, Wd1, W4);
  if (blockIdx.x == 0) {
    float s = 0.f;
    for (int i = threadIdx.x; i < DDIM; i += 256) { float v = dvec[i]; s += v * v; }
#pragma unroll
    for (int off = 1; off < 64; off <<= 1) s += __shfl_xor(s, off);
    __shared__ float cs[4];
    if ((threadIdx.x & 63) == 0) cs[threadIdx.x >> 6] = s;
    __syncthreads();
    if (threadIdx.x == 0) Cout[0] = sqrtf(cs[0] + cs[1] + cs[2] + cs[3]);
  }
}

// ------- GEMM chunk: 2 M-frags x NFW N-frags, f16 single-W, 2-deep prefetch -------
// XOR-unit swizzle folds into the per-thread base (g' = g ^ (l15&3)); k-loop A
// addresses are base + ks*64 compile-time offsets -> zero per-k-step VALU.
template <int NKS, int NFW>
__device__ __forceinline__ void gemmN(const char* ip, const u16* __restrict__ W,
                                      int nb0, int l15, int g, f32x4 (&acc)[2][NFW]) {
  const int lof = (g << 7) + (l15 << 3);
  const int gs = g ^ (l15 & 3);                 // swizzled unit low bits
  const char* a0b = ip + l15 * PROW + gs * 16;
  const char* a1b = a0b + 16 * PROW;            // (l15+16)&3 == l15&3 -> same gs
  const u16* wp[NFW];
#pragma unroll
  for (int nf = 0; nf < NFW; ++nf)
    wp[nf] = W + ((((size_t)(nb0 + nf) * NKS) << 9) + lof);
  f16x8 b[NFW][3];
#pragma unroll
  for (int nf = 0; nf < NFW; ++nf) b[nf][0] = *(const f16x8*)wp[nf];
  if (NKS > 1) {
#pragma unroll
    for (int nf = 0; nf < NFW; ++nf) b[nf][1] = *(const f16x8*)(wp[nf] + 512);
  }
#pragma unroll
  for (int ks = 0; ks < NKS; ++ks) {
    const int cur = ks % 3;
    if (ks + 2 < NKS) {
      const int nxt = (ks + 2) % 3;
#pragma unroll
      for (int nf = 0; nf < NFW; ++nf)
        b[nf][nxt] = *(const f16x8*)(wp[nf] + (size_t)(ks + 2) * 512);
    }
    const f16x8 a0 = *(const f16x8*)(a0b + ks * 64);
    const f16x8 a1 = *(const f16x8*)(a1b + ks * 64);
    __builtin_amdgcn_s_setprio(1);
#pragma unroll
    for (int nf = 0; nf < NFW; ++nf) {
      acc[0][nf] = __builtin_amdgcn_mfma_f32_16x16x32_f16(a0, b[nf][cur], acc[0][nf], 0, 0, 0);
      acc[1][nf] = __builtin_amdgcn_mfma_f32_16x16x32_f16(a1, b[nf][cur], acc[1][nf], 0, 0, 0);
    }
    __builtin_amdgcn_s_setprio(0);
  }
}

// ---------------- activation epilogue: bias + lrelu -> OUT plane (f16, XOR-swz) -----
template <int NFW>
__device__ __forceinline__ void epiN(f32x4 (&acc)[2][NFW], const float* __restrict__ bias,
                                     int nb0, char* op, int l15, int g) {
#pragma unroll
  for (int nf = 0; nf < NFW; ++nf) {
    const int col = (nb0 + nf) * 16 + l15;
    const float bv = (col < HREAL) ? bias[col] : 0.f;
    const int cu = col >> 3;            // 16B unit
    const int crem = (col & 7) * 2;     // byte within unit
#pragma unroll
    for (int mf = 0; mf < 2; ++mf) {
#pragma unroll
      for (int j = 0; j < 4; ++j) {
        const int row = mf * 16 + g * 4 + j;
        float v = acc[mf][nf][j] + bv;
        v = fmaxf(v, 0.1f * v);
        *(u16*)(op + row * PROW + ((cu ^ (row & 3)) << 4) + crem) = f2h(v);
      }
    }
  }
}

// ---- one hidden layer: 7 chunks {4,4,4,4,4,4,2} round-robin over 4 waves ----
template <int NKS>
__device__ __forceinline__ void layerN(const char* ip, char* op,
                                       const u16* __restrict__ W,
                                       const float* __restrict__ bias,
                                       int wid, int l15, int g) {
  for (int ci = wid; ci < 7; ci += 4) {
    const int nb0 = 4 * ci;
    if (ci == 6) {
      f32x4 acc[2][2] = {};
      gemmN<NKS, 2>(ip, W, nb0, l15, g, acc);
      epiN<2>(acc, bias, nb0, op, l15, g);
    } else {
      f32x4 acc[2][4] = {};
      gemmN<NKS, 4>(ip, W, nb0, l15, g, acc);
      epiN<4>(acc, bias, nb0, op, l15, g);
    }
  }
}

// ---- L6 chunk: gemm + tanh + y-store + fused partial A/B/M ----
template <int NFW>
__device__ __forceinline__ void l6N(const char* ip, const u16* __restrict__ W6,
                                    const float* __restrict__ bd3,
                                    const float* __restrict__ dvec,
                                    const float* __restrict__ xin,
                                    float* __restrict__ y_out,
                                    size_t row0, int nb0, int l15, int g,
                                    float (&pA)[2][4], float (&pB)[2][4], float (&pM)[2][4]) {
  f32x4 acc[2][NFW] = {};
  gemmN<13, NFW>(ip, W6, nb0, l15, g, acc);
#pragma unroll
  for (int mf = 0; mf < 2; ++mf) {
#pragma unroll
    for (int j = 0; j < 4; ++j) {
      const size_t grow = row0 + mf * 16 + g * 4 + j;
#pragma unroll
      for (int nf = 0; nf < NFW; ++nf) {
        const int col = (nb0 + nf) * 16 + l15;
        const float v = acc[mf][nf][j] + bd3[col];
        const float e = __expf(2.f * v);
        const float y = 1.f - 2.f * __builtin_amdgcn_rcpf(e + 1.f);
        y_out[grow * DDIM + col] = y;
        pA[mf][j] = fmaf(y, dvec[col], pA[mf][j]);
        pB[mf][j] = fmaf(y, y, pB[mf][j]);
        const float df = y - xin[grow * DDIM + col];
        pM[mf][j] = fmaf(df, df, pM[mf][j]);
      }
    }
  }
}

// ---------------- main fused kernel: 32 rows per block, 256 threads ----------------
// Ping-pong planes; L3/L4 are MFMA too (z as a K=32 A-fragment in the plane).
__global__ __launch_bounds__(256, 3) void k_main(
    const float* __restrict__ xin, const float* __restrict__ dvec,
    const float* __restrict__ be1, const float* __restrict__ be2, const float* __restrict__ be3,
    const float* __restrict__ bd1, const float* __restrict__ bd2, const float* __restrict__ bd3,
    const u16* __restrict__ W1, const u16* __restrict__ W2,
    const u16* __restrict__ W5, const u16* __restrict__ W6,
    const u16* __restrict__ W3, const u16* __restrict__ W4,
    const float* __restrict__ Cptr,
    float* __restrict__ y_out, float* __restrict__ z_out,
    float* __restrict__ defen, float* __restrict__ msep) {
  extern __shared__ __align__(16) char lds[];
  char* pa = lds;              // plane A
  char* pb = lds + PLANE;      // plane B

  const int tid = threadIdx.x;
  const int lane = tid & 63;
  const int wid = tid >> 6;       // 0..3
  const int l15 = lane & 15;
  const int g = lane >> 4;        // 0..3
  const size_t row0 = (size_t)blockIdx.x * ROWS;

  // ---- stage x -> plane A (f16, XOR-swz units) ----
#pragma unroll
  for (int i = 0; i < 7; ++i) {
    const int f = i * 256 + tid;                 // 32 rows * 56 float4 = 1792
    const int r = f / 56, c4 = f - r * 56;
    const float4 v = *(const float4*)(xin + (row0 + r) * DDIM + c4 * 4);
    const float vv[4] = {v.x, v.y, v.z, v.w};
    ushort4 hh;
    u16* hw = (u16*)&hh;
#pragma unroll
    for (int w = 0; w < 4; ++w) hw[w] = f2h(vv[w]);
    *(ushort4*)(pa + r * PROW + (((c4 >> 1) ^ (r & 3)) << 4) + (c4 & 1) * 8) = hh;
  }
  __syncthreads();

  // ---- L1: x(A) -> h1(B) ----
  layerN<7>(pa, pb, W1, be1, wid, l15, g);
  __syncthreads();

  // ---- L2: h1(B) -> h2(A) ----
  layerN<13>(pb, pa, W2, be2, wid, l15, g);
  __syncthreads();

  // ---- L3 (MFMA): z = h2(A) @ We3 + be3; wave 0 only ----
  // Output z scattered into plane B as a ready A-fragment (K=32, k<4 real).
  if (wid == 0) {
    f32x4 acc3[2][1] = {};
    gemmN<13, 1>(pa, W3, 0, l15, g, acc3);
    float zv[2][4];
#pragma unroll
    for (int mf = 0; mf < 2; ++mf) {
#pragma unroll
      for (int j = 0; j < 4; ++j) {
        const float s = acc3[mf][0][j] + ((l15 < 4) ? be3[l15] : 0.f);
        zv[mf][j] = s;
        if (l15 < 4) z_out[(row0 + mf * 16 + g * 4 + j) * 4 + l15] = s;
      }
    }
    // pack z (k=0..3) into unit 0; zero units 1..3 (k=8..31) of each row
#pragma unroll
    for (int mf = 0; mf < 2; ++mf) {
#pragma unroll
      for (int j = 0; j < 4; ++j) {
        const float z0 = __shfl(zv[mf][j], (lane & ~15) + 0);
        const float z1 = __shfl(zv[mf][j], (lane & ~15) + 1);
        const float z2 = __shfl(zv[mf][j], (lane & ~15) + 2);
        const float z3 = __shfl(zv[mf][j], (lane & ~15) + 3);
        if (l15 < 4) {
          const int r = mf * 16 + g * 4 + j;
          uint4 zq = {0u, 0u, 0u, 0u};
          if (l15 == 0) {
            zq.x = (u32)f2h(z0) | ((u32)f2h(z1) << 16);
            zq.y = (u32)f2h(z2) | ((u32)f2h(z3) << 16);
          }
          *(uint4*)(pb + r * PROW + ((l15 ^ (r & 3)) << 4)) = zq;
        }
      }
    }
  }
  __syncthreads();

  // ---- L4 (MFMA): g1 = lrelu(z(B) @ Wd1 + bd1) -> plane A ----
  layerN<1>(pb, pa, W4, bd1, wid, l15, g);
  __syncthreads();

  // ---- L5: g2 = lrelu(g1(A) @ Wd2 + bd2) -> plane B ----
  layerN<13>(pa, pb, W5, bd2, wid, l15, g);
  __syncthreads();                 // A now free (red overlay), B holds g2

  // ---- L6: y = tanh(g2(B) @ Wd3 + bd3) + fused reductions ----
  // 14 nb in 4 chunks {4,4,4,2}; wave w takes chunk w.
  {
    float pA[2][4] = {}, pB[2][4] = {}, pM[2][4] = {};
    if (wid < 3) l6N<4>(pb, W6, bd3, dvec, xin, y_out, row0, 4 * wid, l15, g, pA, pB, pM);
    else         l6N<2>(pb, W6, bd3, dvec, xin, y_out, row0, 12,      l15, g, pA, pB, pM);
    float* red = (float*)pa;       // [32 rows][4 waves][4]
#pragma unroll
    for (int mf = 0; mf < 2; ++mf) {
#pragma unroll
      for (int j = 0; j < 4; ++j) {
        float a = pA[mf][j], b = pB[mf][j], m = pM[mf][j];
#pragma unroll
        for (int off = 1; off < 16; off <<= 1) {
          a += __shfl_xor(a, off);
          b += __shfl_xor(b, off);
          m += __shfl_xor(m, off);
        }
        if (l15 == 0) {
          const int lrow = mf * 16 + g * 4 + j;
          red[(lrow * 4 + wid) * 4 + 0] = a;
          red[(lrow * 4 + wid) * 4 + 1] = b;
          red[(lrow * 4 + wid) * 4 + 2] = m;
        }
      }
    }
  }
  __syncthreads();

  if (tid < 32) {
    const float Cn = Cptr[0];
    const float* red = (const float*)pa;
    float A = 0.f, B2 = 0.f, M = 0.f;
#pragma unroll
    for (int w = 0; w < 4; ++w) {
      A  += red[(tid * 4 + w) * 4 + 0];
      B2 += red[(tid * 4 + w) * 4 + 1];
      M  += red[(tid * 4 + w) * 4 + 2];
    }
    defen[row0 + tid] = A / (sqrtf(B2) * Cn + 1e-5f);
#pragma unroll
    for (int off = 1; off < 32; off <<= 1) M += __shfl_xor(M, off);
    if (tid == 0) msep[blockIdx.x] = M;
  }
}

// ---------------- top-k stage A: 64 blocks, per-block top-20 of 2048 ----------------
__global__ void k_topk_a(const float* __restrict__ defen, float* __restrict__ cand) {
  __shared__ float vals[2048];
  __shared__ float wv[4];
  __shared__ int wi[4];
  const int tid = threadIdx.x;
  const int base = blockIdx.x * 2048;
  for (int i = tid; i < 2048; i += 256) vals[i] = defen[base + i];
  __syncthreads();
  for (int it = 0; it < 20; ++it) {
    float mv = -1e30f; int mi = 1 << 30;
    for (int i = tid; i < 2048; i += 256) {
      float v = vals[i];
      if (v > mv) { mv = v; mi = i; }
    }
#pragma unroll
    for (int off = 1; off < 64; off <<= 1) {
      float ov = __shfl_xor(mv, off); int oi = __shfl_xor(mi, off);
      if (ov > mv || (ov == mv && oi < mi)) { mv = ov; mi = oi; }
    }
    if ((tid & 63) == 0) { wv[tid >> 6] = mv; wi[tid >> 6] = mi; }
    __syncthreads();
    if (tid == 0) {
      float bv = wv[0]; int bi = wi[0];
      for (int q = 1; q < 4; ++q)
        if (wv[q] > bv || (wv[q] == bv && wi[q] < bi)) { bv = wv[q]; bi = wi[q]; }
      cand[blockIdx.x * 20 + it] = bv;
      vals[bi] = -1e30f;
    }
    __syncthreads();
  }
}

// ---------------- top-k stage B: final top-20 of 1280 + R_loss ----------------
__global__ void k_topk_b(const float* __restrict__ cand, const float* __restrict__ msep,
                         float* __restrict__ rloss) {
  __shared__ float vals[1280];
  __shared__ float wv[4];
  __shared__ int wi[4];
  __shared__ float msum[4];
  const int tid = threadIdx.x;
  for (int i = tid; i < 1280; i += 256) vals[i] = cand[i];
  float ms = 0.f;
  for (int i = tid; i < 4096; i += 256) ms += msep[i];
#pragma unroll
  for (int off = 1; off < 64; off <<= 1) ms += __shfl_xor(ms, off);
  if ((tid & 63) == 0) msum[tid >> 6] = ms;
  __syncthreads();
  float sam = 0.f;
  for (int it = 0; it < 20; ++it) {
    float mv = -1e30f; int mi = 1 << 30;
    for (int i = tid; i < 1280; i += 256) {
      float v = vals[i];
      if (v > mv) { mv = v; mi = i; }
    }
#pragma unroll
    for (int off = 1; off < 64; off <<= 1) {
      float ov = __shfl_xor(mv, off); int oi = __shfl_xor(mi, off);
      if (ov > mv || (ov == mv && oi < mi)) { mv = ov; mi = oi; }
    }
    if ((tid & 63) == 0) { wv[tid >> 6] = mv; wi[tid >> 6] = mi; }
    __syncthreads();
    if (tid == 0) {
      float bv = wv[0]; int bi = wi[0];
      for (int q = 1; q < 4; ++q)
        if (wv[q] > bv || (wv[q] == bv && wi[q] < bi)) { bv = wv[q]; bi = wi[q]; }
      sam += bv;
      vals[bi] = -1e30f;
    }
    __syncthreads();
  }
  if (tid == 0) {
    float mse = (msum[0] + msum[1] + msum[2] + msum[3]) / 29360128.f;  // N*D
    rloss[0] = mse + 0.1f * sam;
  }
}

extern "C" void kernel_launch(void* const* d_in, const int* in_sizes, int n_in,
                              void* d_out, int out_size, void* d_ws, size_t ws_size,
                              hipStream_t stream) {
  const float* x    = (const float*)d_in[0];
  const float* dinp = (const float*)d_in[1];
  const float* We1  = (const float*)d_in[2];
  const float* be1  = (const float*)d_in[3];
  const float* We2  = (const float*)d_in[4];
  const float* be2  = (const float*)d_in[5];
  const float* We3  = (const float*)d_in[6];
  const float* be3  = (const float*)d_in[7];
  const float* Wd1  = (const float*)d_in[8];
  const float* bd1  = (const float*)d_in[9];
  const float* Wd2  = (const float*)d_in[10];
  const float* bd2  = (const float*)d_in[11];
  const float* Wd3  = (const float*)d_in[12];
  const float* bd3  = (const float*)d_in[13];

  float* y_out = (float*)d_out;
  float* z_out = y_out + (size_t)NROWS * DDIM;
  float* r_out = z_out + (size_t)NROWS * 4;

  char* ws = (char*)d_ws;
  u16* W1 = (u16*)(ws + OFF_W1);
  u16* W2 = (u16*)(ws + OFF_W2);
  u16* W5 = (u16*)(ws + OFF_W5);
  u16* W6 = (u16*)(ws + OFF_W6);
  u16* W3 = (u16*)(ws + OFF_W3);
  u16* W4 = (u16*)(ws + OFF_W4);
  float* Cf    = (float*)(ws + OFF_C);
  float* msep  = (float*)(ws + OFF_MSEP);
  float* defen = (float*)(ws + OFF_DEFEN);
  float* cand  = (float*)(ws + OFF_CAND);

  (void)hipFuncSetAttribute((const void*)k_main, hipFuncAttributeMaxDynamicSharedMemorySize, LDS_TOTAL);

  k_prep<<<dim3(256), dim3(256), 0, stream>>>(We1, We2, Wd2, Wd3, We3, Wd1, dinp,
                                              W1, W2, W5, W6, W3, W4, Cf);
  k_main<<<dim3(4096), dim3(256), LDS_TOTAL, stream>>>(x, dinp, be1, be2, be3, bd1, bd2, bd3,
                                                       W1, W2, W5, W6, W3, W4,
                                                       Cf, y_out, z_out, defen, msep);
  k_topk_a<<<dim3(64), dim3(256), 0, stream>>>(defen, cand);
  k_topk_b<<<dim3(1), dim3(256), 0, stream>>>(cand, msep, r_out);
}

// Round 26
// 303.005 us; speedup vs baseline: 1.0964x; 1.0959x over previous
//
#include <hip/hip_runtime.h>
#include <hip/hip_bf16.h>
#include <math.h>

typedef _Float16 f16x8 __attribute__((ext_vector_type(8)));
typedef float f32x4 __attribute__((ext_vector_type(4)));
typedef unsigned int u32;
typedef unsigned short u16;

#define NROWS 131072
#define DDIM 224
#define HREAL 400
#define HP 416          // padded hidden dim (13*32)
#define ROWS 32         // rows per block
#define PROW 832        // 52 units of 16B; XOR-unit swizzle (unit ^ (row&3))
#define PLANE 26624     // one plane: 32 * 832
#define LDS_TOTAL 53248 // plane A + plane B; 3 blocks/CU

// ---- workspace layout (bytes); weights single-f16 fragment-linear ----
#define OFF_W1    0          // [26nb][7ks][4g][16l][8] u16 = 186368 B
#define OFF_W2    186368     // [26][13][4][16][8] = 346112 B
#define OFF_W5    532480     // 346112 B
#define OFF_W6    878592     // [14][13][4][16][8] = 186368 B
#define OFF_W3    1064960    // [1][13][4][16][8] = 13312 B  (We3 as B-frag, N=16 cols<4 real)
#define OFF_W4    1078272    // [26][1][4][16][8] = 26624 B  (Wd1 as B-frag, K=32 k<4 real)
#define OFF_C     1104896    // f32 scalar ||d||
#define OFF_MSEP  1104912    // f32 [4096]
#define OFF_DEFEN 1121296    // f32 [131072]
#define OFF_CAND  1645584    // f32 [1280]
// total 1650704 bytes

__device__ __forceinline__ u16 f2h(float v) {
  union { _Float16 h; u16 u; } c;
  c.h = (_Float16)v;
  return c.u;
}

// single-f16 fragment packing: u16 index i -> (nb, ks, g, l15, e)
__device__ __forceinline__ void pack8(int i, int NKS, int KREAL, int NREAL, int NLD,
                                      const float* __restrict__ W,
                                      u16* __restrict__ Wo) {
  const int e = i & 7, l15 = (i >> 3) & 15, g = (i >> 7) & 3;
  const int rest = i >> 9;
  const int ks = rest % NKS, nb = rest / NKS;
  const int n = nb * 16 + l15, k = ks * 32 + g * 8 + e;
  const float w = (n < NREAL && k < KREAL) ? W[k * NLD + n] : 0.f;
  Wo[i] = f2h(w);
}

__global__ void k_prep(const float* __restrict__ We1, const float* __restrict__ We2,
                       const float* __restrict__ Wd2, const float* __restrict__ Wd3,
                       const float* __restrict__ We3, const float* __restrict__ Wd1,
                       const float* __restrict__ dvec,
                       u16* __restrict__ W1, u16* __restrict__ W2,
                       u16* __restrict__ W5, u16* __restrict__ W6,
                       u16* __restrict__ W3, u16* __restrict__ W4,
                       float* __restrict__ Cout) {
  const int t = blockIdx.x * 256 + threadIdx.x;
  const int NT = gridDim.x * 256;
  for (int i = t; i < 26 * 7 * 512;  i += NT) pack8(i, 7,  DDIM,  HREAL, HREAL, We1, W1);
  for (int i = t; i < 26 * 13 * 512; i += NT) pack8(i, 13, HREAL, HREAL, HREAL, We2, W2);
  for (int i = t; i < 26 * 13 * 512; i += NT) pack8(i, 13, HREAL, HREAL, HREAL, Wd2, W5);
  for (int i = t; i < 14 * 13 * 512; i += NT) pack8(i, 13, HREAL, DDIM,  DDIM,  Wd3, W6);
  for (int i = t; i < 1 * 13 * 512;  i += NT) pack8(i, 13, HREAL, 4,     4,     We3, W3);
  for (int i = t; i < 26 * 1 * 512;  i += NT) pack8(i, 1,  4,     HREAL, HREAL, Wd1, W4);
  if (blockIdx.x == 0) {
    float s = 0.f;
    for (int i = threadIdx.x; i < DDIM; i += 256) { float v = dvec[i]; s += v * v; }
#pragma unroll
    for (int off = 1; off < 64; off <<= 1) s += __shfl_xor(s, off);
    __shared__ float cs[4];
    if ((threadIdx.x & 63) == 0) cs[threadIdx.x >> 6] = s;
    __syncthreads();
    if (threadIdx.x == 0) Cout[0] = sqrtf(cs[0] + cs[1] + cs[2] + cs[3]);
  }
}

// ------- GEMM chunk: 2 M-frags x NFW N-frags, f16 single-W, depth-1 prefetch -------
// R14's proven copy-forward pattern (no spill at this register shape). XOR-unit
// swizzle folds into the per-thread base; k-loop A addresses are compile-time.
template <int NKS, int NFW>
__device__ __forceinline__ void gemmN(const char* ip, const u16* __restrict__ W,
                                      int nb0, int l15, int g, f32x4 (&acc)[2][NFW]) {
  const int lof = (g << 7) + (l15 << 3);
  const int gs = g ^ (l15 & 3);                 // swizzled unit low bits
  const char* a0b = ip + l15 * PROW + gs * 16;
  const char* a1b = a0b + 16 * PROW;            // (l15+16)&3 == l15&3 -> same gs
  const u16* wp[NFW];
#pragma unroll
  for (int nf = 0; nf < NFW; ++nf)
    wp[nf] = W + ((((size_t)(nb0 + nf) * NKS) << 9) + lof);
  f16x8 bc[NFW];
#pragma unroll
  for (int nf = 0; nf < NFW; ++nf) bc[nf] = *(const f16x8*)wp[nf];
#pragma unroll
  for (int ks = 0; ks < NKS; ++ks) {
    f16x8 bn[NFW];
    if (ks + 1 < NKS) {
#pragma unroll
      for (int nf = 0; nf < NFW; ++nf)
        bn[nf] = *(const f16x8*)(wp[nf] + (size_t)(ks + 1) * 512);
    }
    const f16x8 a0 = *(const f16x8*)(a0b + ks * 64);
    const f16x8 a1 = *(const f16x8*)(a1b + ks * 64);
    __builtin_amdgcn_s_setprio(1);
#pragma unroll
    for (int nf = 0; nf < NFW; ++nf) {
      acc[0][nf] = __builtin_amdgcn_mfma_f32_16x16x32_f16(a0, bc[nf], acc[0][nf], 0, 0, 0);
      acc[1][nf] = __builtin_amdgcn_mfma_f32_16x16x32_f16(a1, bc[nf], acc[1][nf], 0, 0, 0);
    }
    __builtin_amdgcn_s_setprio(0);
    if (ks + 1 < NKS) {
#pragma unroll
      for (int nf = 0; nf < NFW; ++nf) bc[nf] = bn[nf];
    }
  }
}

// ---------------- activation epilogue: bias + lrelu -> OUT plane (f16, XOR-swz) -----
template <int NFW>
__device__ __forceinline__ void epiN(f32x4 (&acc)[2][NFW], const float* __restrict__ bias,
                                     int nb0, char* op, int l15, int g) {
#pragma unroll
  for (int nf = 0; nf < NFW; ++nf) {
    const int col = (nb0 + nf) * 16 + l15;
    const float bv = (col < HREAL) ? bias[col] : 0.f;
    const int cu = col >> 3;            // 16B unit
    const int crem = (col & 7) * 2;     // byte within unit
#pragma unroll
    for (int mf = 0; mf < 2; ++mf) {
#pragma unroll
      for (int j = 0; j < 4; ++j) {
        const int row = mf * 16 + g * 4 + j;
        float v = acc[mf][nf][j] + bv;
        v = fmaxf(v, 0.1f * v);
        *(u16*)(op + row * PROW + ((cu ^ (row & 3)) << 4) + crem) = f2h(v);
      }
    }
  }
}

// ---- one hidden layer: 7 chunks {4,4,4,4,4,4,2} round-robin over 4 waves ----
template <int NKS>
__device__ __forceinline__ void layerN(const char* ip, char* op,
                                       const u16* __restrict__ W,
                                       const float* __restrict__ bias,
                                       int wid, int l15, int g) {
  for (int ci = wid; ci < 7; ci += 4) {
    const int nb0 = 4 * ci;
    if (ci == 6) {
      f32x4 acc[2][2] = {};
      gemmN<NKS, 2>(ip, W, nb0, l15, g, acc);
      epiN<2>(acc, bias, nb0, op, l15, g);
    } else {
      f32x4 acc[2][4] = {};
      gemmN<NKS, 4>(ip, W, nb0, l15, g, acc);
      epiN<4>(acc, bias, nb0, op, l15, g);
    }
  }
}

// ---- L6 chunk: gemm + tanh + y-store + fused partial A/B/M ----
template <int NFW>
__device__ __forceinline__ void l6N(const char* ip, const u16* __restrict__ W6,
                                    const float* __restrict__ bd3,
                                    const float* __restrict__ dvec,
                                    const float* __restrict__ xin,
                                    float* __restrict__ y_out,
                                    size_t row0, int nb0, int l15, int g,
                                    float (&pA)[2][4], float (&pB)[2][4], float (&pM)[2][4]) {
  f32x4 acc[2][NFW] = {};
  gemmN<13, NFW>(ip, W6, nb0, l15, g, acc);
#pragma unroll
  for (int mf = 0; mf < 2; ++mf) {
#pragma unroll
    for (int j = 0; j < 4; ++j) {
      const size_t grow = row0 + mf * 16 + g * 4 + j;
#pragma unroll
      for (int nf = 0; nf < NFW; ++nf) {
        const int col = (nb0 + nf) * 16 + l15;
        const float v = acc[mf][nf][j] + bd3[col];
        const float e = __expf(2.f * v);
        const float y = 1.f - 2.f * __builtin_amdgcn_rcpf(e + 1.f);
        y_out[grow * DDIM + col] = y;
        pA[mf][j] = fmaf(y, dvec[col], pA[mf][j]);
        pB[mf][j] = fmaf(y, y, pB[mf][j]);
        const float df = y - xin[grow * DDIM + col];
        pM[mf][j] = fmaf(df, df, pM[mf][j]);
      }
    }
  }
}

// ---------------- main fused kernel: 32 rows per block, 256 threads ----------------
// Ping-pong planes; L3/L4 are MFMA too (z as a K=32 A-fragment in the plane).
__global__ __launch_bounds__(256, 3) void k_main(
    const float* __restrict__ xin, const float* __restrict__ dvec,
    const float* __restrict__ be1, const float* __restrict__ be2, const float* __restrict__ be3,
    const float* __restrict__ bd1, const float* __restrict__ bd2, const float* __restrict__ bd3,
    const u16* __restrict__ W1, const u16* __restrict__ W2,
    const u16* __restrict__ W5, const u16* __restrict__ W6,
    const u16* __restrict__ W3, const u16* __restrict__ W4,
    const float* __restrict__ Cptr,
    float* __restrict__ y_out, float* __restrict__ z_out,
    float* __restrict__ defen, float* __restrict__ msep) {
  extern __shared__ __align__(16) char lds[];
  char* pa = lds;              // plane A
  char* pb = lds + PLANE;      // plane B

  const int tid = threadIdx.x;
  const int lane = tid & 63;
  const int wid = tid >> 6;       // 0..3
  const int l15 = lane & 15;
  const int g = lane >> 4;        // 0..3
  const size_t row0 = (size_t)blockIdx.x * ROWS;

  // ---- stage x -> plane A (f16, XOR-swz units) ----
#pragma unroll
  for (int i = 0; i < 7; ++i) {
    const int f = i * 256 + tid;                 // 32 rows * 56 float4 = 1792
    const int r = f / 56, c4 = f - r * 56;
    const float4 v = *(const float4*)(xin + (row0 + r) * DDIM + c4 * 4);
    const float vv[4] = {v.x, v.y, v.z, v.w};
    ushort4 hh;
    u16* hw = (u16*)&hh;
#pragma unroll
    for (int w = 0; w < 4; ++w) hw[w] = f2h(vv[w]);
    *(ushort4*)(pa + r * PROW + (((c4 >> 1) ^ (r & 3)) << 4) + (c4 & 1) * 8) = hh;
  }
  __syncthreads();

  // ---- L1: x(A) -> h1(B) ----
  layerN<7>(pa, pb, W1, be1, wid, l15, g);
  __syncthreads();

  // ---- L2: h1(B) -> h2(A) ----
  layerN<13>(pb, pa, W2, be2, wid, l15, g);
  __syncthreads();

  // ---- L3 (MFMA): z = h2(A) @ We3 + be3; wave 0 only ----
  // Output z scattered into plane B as a ready A-fragment (K=32, k<4 real).
  if (wid == 0) {
    f32x4 acc3[2][1] = {};
    gemmN<13, 1>(pa, W3, 0, l15, g, acc3);
    float zv[2][4];
#pragma unroll
    for (int mf = 0; mf < 2; ++mf) {
#pragma unroll
      for (int j = 0; j < 4; ++j) {
        const float s = acc3[mf][0][j] + ((l15 < 4) ? be3[l15] : 0.f);
        zv[mf][j] = s;
        if (l15 < 4) z_out[(row0 + mf * 16 + g * 4 + j) * 4 + l15] = s;
      }
    }
    // pack z (k=0..3) into unit 0; zero units 1..3 (k=8..31) of each row
#pragma unroll
    for (int mf = 0; mf < 2; ++mf) {
#pragma unroll
      for (int j = 0; j < 4; ++j) {
        const float z0 = __shfl(zv[mf][j], (lane & ~15) + 0);
        const float z1 = __shfl(zv[mf][j], (lane & ~15) + 1);
        const float z2 = __shfl(zv[mf][j], (lane & ~15) + 2);
        const float z3 = __shfl(zv[mf][j], (lane & ~15) + 3);
        if (l15 < 4) {
          const int r = mf * 16 + g * 4 + j;
          uint4 zq = {0u, 0u, 0u, 0u};
          if (l15 == 0) {
            zq.x = (u32)f2h(z0) | ((u32)f2h(z1) << 16);
            zq.y = (u32)f2h(z2) | ((u32)f2h(z3) << 16);
          }
          *(uint4*)(pb + r * PROW + ((l15 ^ (r & 3)) << 4)) = zq;
        }
      }
    }
  }
  __syncthreads();

  // ---- L4 (MFMA): g1 = lrelu(z(B) @ Wd1 + bd1) -> plane A ----
  layerN<1>(pb, pa, W4, bd1, wid, l15, g);
  __syncthreads();

  // ---- L5: g2 = lrelu(g1(A) @ Wd2 + bd2) -> plane B ----
  layerN<13>(pa, pb, W5, bd2, wid, l15, g);
  __syncthreads();                 // A now free (red overlay), B holds g2

  // ---- L6: y = tanh(g2(B) @ Wd3 + bd3) + fused reductions ----
  // 14 nb in 4 chunks {4,4,4,2}; wave w takes chunk w.
  {
    float pA[2][4] = {}, pB[2][4] = {}, pM[2][4] = {};
    if (wid < 3) l6N<4>(pb, W6, bd3, dvec, xin, y_out, row0, 4 * wid, l15, g, pA, pB, pM);
    else         l6N<2>(pb, W6, bd3, dvec, xin, y_out, row0, 12,      l15, g, pA, pB, pM);
    float* red = (float*)pa;       // [32 rows][4 waves][4]
#pragma unroll
    for (int mf = 0; mf < 2; ++mf) {
#pragma unroll
      for (int j = 0; j < 4; ++j) {
        float a = pA[mf][j], b = pB[mf][j], m = pM[mf][j];
#pragma unroll
        for (int off = 1; off < 16; off <<= 1) {
          a += __shfl_xor(a, off);
          b += __shfl_xor(b, off);
          m += __shfl_xor(m, off);
        }
        if (l15 == 0) {
          const int lrow = mf * 16 + g * 4 + j;
          red[(lrow * 4 + wid) * 4 + 0] = a;
          red[(lrow * 4 + wid) * 4 + 1] = b;
          red[(lrow * 4 + wid) * 4 + 2] = m;
        }
      }
    }
  }
  __syncthreads();

  if (tid < 32) {
    const float Cn = Cptr[0];
    const float* red = (const float*)pa;
    float A = 0.f, B2 = 0.f, M = 0.f;
#pragma unroll
    for (int w = 0; w < 4; ++w) {
      A  += red[(tid * 4 + w) * 4 + 0];
      B2 += red[(tid * 4 + w) * 4 + 1];
      M  += red[(tid * 4 + w) * 4 + 2];
    }
    defen[row0 + tid] = A / (sqrtf(B2) * Cn + 1e-5f);
#pragma unroll
    for (int off = 1; off < 32; off <<= 1) M += __shfl_xor(M, off);
    if (tid == 0) msep[blockIdx.x] = M;
  }
}

// ---------------- top-k stage A: 64 blocks, per-block top-20 of 2048 ----------------
__global__ void k_topk_a(const float* __restrict__ defen, float* __restrict__ cand) {
  __shared__ float vals[2048];
  __shared__ float wv[4];
  __shared__ int wi[4];
  const int tid = threadIdx.x;
  const int base = blockIdx.x * 2048;
  for (int i = tid; i < 2048; i += 256) vals[i] = defen[base + i];
  __syncthreads();
  for (int it = 0; it < 20; ++it) {
    float mv = -1e30f; int mi = 1 << 30;
    for (int i = tid; i < 2048; i += 256) {
      float v = vals[i];
      if (v > mv) { mv = v; mi = i; }
    }
#pragma unroll
    for (int off = 1; off < 64; off <<= 1) {
      float ov = __shfl_xor(mv, off); int oi = __shfl_xor(mi, off);
      if (ov > mv || (ov == mv && oi < mi)) { mv = ov; mi = oi; }
    }
    if ((tid & 63) == 0) { wv[tid >> 6] = mv; wi[tid >> 6] = mi; }
    __syncthreads();
    if (tid == 0) {
      float bv = wv[0]; int bi = wi[0];
      for (int q = 1; q < 4; ++q)
        if (wv[q] > bv || (wv[q] == bv && wi[q] < bi)) { bv = wv[q]; bi = wi[q]; }
      cand[blockIdx.x * 20 + it] = bv;
      vals[bi] = -1e30f;
    }
    __syncthreads();
  }
}

// ---------------- top-k stage B: final top-20 of 1280 + R_loss ----------------
__global__ void k_topk_b(const float* __restrict__ cand, const float* __restrict__ msep,
                         float* __restrict__ rloss) {
  __shared__ float vals[1280];
  __shared__ float wv[4];
  __shared__ int wi[4];
  __shared__ float msum[4];
  const int tid = threadIdx.x;
  for (int i = tid; i < 1280; i += 256) vals[i] = cand[i];
  float ms = 0.f;
  for (int i = tid; i < 4096; i += 256) ms += msep[i];
#pragma unroll
  for (int off = 1; off < 64; off <<= 1) ms += __shfl_xor(ms, off);
  if ((tid & 63) == 0) msum[tid >> 6] = ms;
  __syncthreads();
  float sam = 0.f;
  for (int it = 0; it < 20; ++it) {
    float mv = -1e30f; int mi = 1 << 30;
    for (int i = tid; i < 1280; i += 256) {
      float v = vals[i];
      if (v > mv) { mv = v; mi = i; }
    }
#pragma unroll
    for (int off = 1; off < 64; off <<= 1) {
      float ov = __shfl_xor(mv, off); int oi = __shfl_xor(mi, off);
      if (ov > mv || (ov == mv && oi < mi)) { mv = ov; mi = oi; }
    }
    if ((tid & 63) == 0) { wv[tid >> 6] = mv; wi[tid >> 6] = mi; }
    __syncthreads();
    if (tid == 0) {
      float bv = wv[0]; int bi = wi[0];
      for (int q = 1; q < 4; ++q)
        if (wv[q] > bv || (wv[q] == bv && wi[q] < bi)) { bv = wv[q]; bi = wi[q]; }
      sam += bv;
      vals[bi] = -1e30f;
    }
    __syncthreads();
  }
  if (tid == 0) {
    float mse = (msum[0] + msum[1] + msum[2] + msum[3]) / 29360128.f;  // N*D
    rloss[0] = mse + 0.1f * sam;
  }
}

extern "C" void kernel_launch(void* const* d_in, const int* in_sizes, int n_in,
                              void* d_out, int out_size, void* d_ws, size_t ws_size,
                              hipStream_t stream) {
  const float* x    = (const float*)d_in[0];
  const float* dinp = (const float*)d_in[1];
  const float* We1  = (const float*)d_in[2];
  const float* be1  = (const float*)d_in[3];
  const float* We2  = (const float*)d_in[4];
  const float* be2  = (const float*)d_in[5];
  const float* We3  = (const float*)d_in[6];
  const float* be3  = (const float*)d_in[7];
  const float* Wd1  = (const float*)d_in[8];
  const float* bd1  = (const float*)d_in[9];
  const float* Wd2  = (const float*)d_in[10];
  const float* bd2  = (const float*)d_in[11];
  const float* Wd3  = (const float*)d_in[12];
  const float* bd3  = (const float*)d_in[13];

  float* y_out = (float*)d_out;
  float* z_out = y_out + (size_t)NROWS * DDIM;
  float* r_out = z_out + (size_t)NROWS * 4;

  char* ws = (char*)d_ws;
  u16* W1 = (u16*)(ws + OFF_W1);
  u16* W2 = (u16*)(ws + OFF_W2);
  u16* W5 = (u16*)(ws + OFF_W5);
  u16* W6 = (u16*)(ws + OFF_W6);
  u16* W3 = (u16*)(ws + OFF_W3);
  u16* W4 = (u16*)(ws + OFF_W4);
  float* Cf    = (float*)(ws + OFF_C);
  float* msep  = (float*)(ws + OFF_MSEP);
  float* defen = (float*)(ws + OFF_DEFEN);
  float* cand  = (float*)(ws + OFF_CAND);

  (void)hipFuncSetAttribute((const void*)k_main, hipFuncAttributeMaxDynamicSharedMemorySize, LDS_TOTAL);

  k_prep<<<dim3(256), dim3(256), 0, stream>>>(We1, We2, Wd2, Wd3, We3, Wd1, dinp,
                                              W1, W2, W5, W6, W3, W4, Cf);
  k_main<<<dim3(4096), dim3(256), LDS_TOTAL, stream>>>(x, dinp, be1, be2, be3, bd1, bd2, bd3,
                                                       W1, W2, W5, W6, W3, W4,
                                                       Cf, y_out, z_out, defen, msep);
  k_topk_a<<<dim3(64), dim3(256), 0, stream>>>(defen, cand);
  k_topk_b<<<dim3(1), dim3(256), 0, stream>>>(cand, msep, r_out);
}

// Round 27
// 277.528 us; speedup vs baseline: 1.1970x; 1.0918x over previous
//
#include <hip/hip_runtime.h>
#include <hip/hip_bf16.h>
#include <math.h>

typedef _Float16 f16x8 __attribute__((ext_vector_type(8)));
typedef float f32x4 __attribute__((ext_vector_type(4)));
typedef unsigned int u32;
typedef unsigned short u16;

#define NROWS 131072
#define DDIM 224
#define HREAL 400
#define HP 416          // padded hidden dim (13*32)
#define ROWS 32         // rows per block
#define PROW 832        // 52 units of 16B; XOR-unit swizzle (unit ^ (row&3))
#define PLANE 26624     // one plane: 32 * 832
#define LDS_TOTAL 53248 // plane A + plane B; 3 blocks/CU

// ---- workspace layout (bytes); weights single-f16 fragment-linear ----
#define OFF_W1    0          // [26nb][7ks][4g][16l][8] u16 = 186368 B
#define OFF_W2    186368     // [26][13][4][16][8] = 346112 B
#define OFF_W5    532480     // 346112 B
#define OFF_W6    878592     // [14][13][4][16][8] = 186368 B
#define OFF_W3    1064960    // [1][13][4][16][8] = 13312 B  (We3 as B-frag, N=16 cols<4 real)
#define OFF_W4    1078272    // [26][1][4][16][8] = 26624 B  (Wd1 as B-frag, K=32 k<4 real)
#define OFF_C     1104896    // f32 scalar ||d||
#define OFF_MSEP  1104912    // f32 [4096]
#define OFF_DEFEN 1121296    // f32 [131072]
#define OFF_CAND  1645584    // f32 [1280]
// total 1650704 bytes

__device__ __forceinline__ u16 f2h(float v) {
  union { _Float16 h; u16 u; } c;
  c.h = (_Float16)v;
  return c.u;
}

// single-f16 fragment packing: u16 index i -> (nb, ks, g, l15, e)
__device__ __forceinline__ void pack8(int i, int NKS, int KREAL, int NREAL, int NLD,
                                      const float* __restrict__ W,
                                      u16* __restrict__ Wo) {
  const int e = i & 7, l15 = (i >> 3) & 15, g = (i >> 7) & 3;
  const int rest = i >> 9;
  const int ks = rest % NKS, nb = rest / NKS;
  const int n = nb * 16 + l15, k = ks * 32 + g * 8 + e;
  const float w = (n < NREAL && k < KREAL) ? W[k * NLD + n] : 0.f;
  Wo[i] = f2h(w);
}

__global__ void k_prep(const float* __restrict__ We1, const float* __restrict__ We2,
                       const float* __restrict__ Wd2, const float* __restrict__ Wd3,
                       const float* __restrict__ We3, const float* __restrict__ Wd1,
                       const float* __restrict__ dvec,
                       u16* __restrict__ W1, u16* __restrict__ W2,
                       u16* __restrict__ W5, u16* __restrict__ W6,
                       u16* __restrict__ W3, u16* __restrict__ W4,
                       float* __restrict__ Cout) {
  const int t = blockIdx.x * 256 + threadIdx.x;
  const int NT = gridDim.x * 256;
  for (int i = t; i < 26 * 7 * 512;  i += NT) pack8(i, 7,  DDIM,  HREAL, HREAL, We1, W1);
  for (int i = t; i < 26 * 13 * 512; i += NT) pack8(i, 13, HREAL, HREAL, HREAL, We2, W2);
  for (int i = t; i < 26 * 13 * 512; i += NT) pack8(i, 13, HREAL, HREAL, HREAL, Wd2, W5);
  for (int i = t; i < 14 * 13 * 512; i += NT) pack8(i, 13, HREAL, DDIM,  DDIM,  Wd3, W6);
  for (int i = t; i < 1 * 13 * 512;  i += NT) pack8(i, 13, HREAL, 4,     4,     We3, W3);
  for (int i = t; i < 26 * 1 * 512;  i += NT) pack8(i, 1,  4,     HREAL, HREAL, Wd1, W4);
  if (blockIdx.x == 0) {
    float s = 0.f;
    for (int i = threadIdx.x; i < DDIM; i += 256) { float v = dvec[i]; s += v * v; }
#pragma unroll
    for (int off = 1; off < 64; off <<= 1) s += __shfl_xor(s, off);
    __shared__ float cs[4];
    if ((threadIdx.x & 63) == 0) cs[threadIdx.x >> 6] = s;
    __syncthreads();
    if (threadIdx.x == 0) Cout[0] = sqrtf(cs[0] + cs[1] + cs[2] + cs[3]);
  }
}

// ------- GEMM chunk: 2 M-frags x NFW N-frags, f16 single-W, depth-1 prefetch -------
// XOR-unit swizzle folds into the per-thread base; k-loop A addresses are
// compile-time offsets (zero per-k-step address VALU).
template <int NKS, int NFW>
__device__ __forceinline__ void gemmN(const char* ip, const u16* __restrict__ W,
                                      int nb0, int l15, int g, f32x4 (&acc)[2][NFW]) {
  const int lof = (g << 7) + (l15 << 3);
  const int gs = g ^ (l15 & 3);                 // swizzled unit low bits
  const char* a0b = ip + l15 * PROW + gs * 16;
  const char* a1b = a0b + 16 * PROW;            // (l15+16)&3 == l15&3 -> same gs
  const u16* wp[NFW];
#pragma unroll
  for (int nf = 0; nf < NFW; ++nf)
    wp[nf] = W + ((((size_t)(nb0 + nf) * NKS) << 9) + lof);
  f16x8 bc[NFW];
#pragma unroll
  for (int nf = 0; nf < NFW; ++nf) bc[nf] = *(const f16x8*)wp[nf];
#pragma unroll
  for (int ks = 0; ks < NKS; ++ks) {
    f16x8 bn[NFW];
    if (ks + 1 < NKS) {
#pragma unroll
      for (int nf = 0; nf < NFW; ++nf)
        bn[nf] = *(const f16x8*)(wp[nf] + (size_t)(ks + 1) * 512);
    }
    const f16x8 a0 = *(const f16x8*)(a0b + ks * 64);
    const f16x8 a1 = *(const f16x8*)(a1b + ks * 64);
    __builtin_amdgcn_s_setprio(1);
#pragma unroll
    for (int nf = 0; nf < NFW; ++nf) {
      acc[0][nf] = __builtin_amdgcn_mfma_f32_16x16x32_f16(a0, bc[nf], acc[0][nf], 0, 0, 0);
      acc[1][nf] = __builtin_amdgcn_mfma_f32_16x16x32_f16(a1, bc[nf], acc[1][nf], 0, 0, 0);
    }
    __builtin_amdgcn_s_setprio(0);
    if (ks + 1 < NKS) {
#pragma unroll
      for (int nf = 0; nf < NFW; ++nf) bc[nf] = bn[nf];
    }
  }
}

// ---------------- activation epilogue: bias + lrelu -> OUT plane (f16, XOR-swz) -----
template <int NFW>
__device__ __forceinline__ void epiN(f32x4 (&acc)[2][NFW], const float* __restrict__ bias,
                                     int nb0, char* op, int l15, int g) {
#pragma unroll
  for (int nf = 0; nf < NFW; ++nf) {
    const int col = (nb0 + nf) * 16 + l15;
    const float bv = (col < HREAL) ? bias[col] : 0.f;
    const int cu = col >> 3;            // 16B unit
    const int crem = (col & 7) * 2;     // byte within unit
#pragma unroll
    for (int mf = 0; mf < 2; ++mf) {
#pragma unroll
      for (int j = 0; j < 4; ++j) {
        const int row = mf * 16 + g * 4 + j;
        float v = acc[mf][nf][j] + bv;
        v = fmaxf(v, 0.1f * v);
        *(u16*)(op + row * PROW + ((cu ^ (row & 3)) << 4) + crem) = f2h(v);
      }
    }
  }
}

// ---- one hidden layer: balanced wave split {7,7,6,6} of 26 nb ----
// w0: [0,4)+[14,17)  w1: [4,8)+[17,20)  w2: [8,11)+[20,23)  w3: [11,14)+[23,26)
// Critical path 7 nb (was 8 with round-robin).
template <int NKS>
__device__ __forceinline__ void layerN(const char* ip, char* op,
                                       const u16* __restrict__ W,
                                       const float* __restrict__ bias,
                                       int wid, int l15, int g) {
  if (wid < 2) {
    {
      f32x4 acc[2][4] = {};
      gemmN<NKS, 4>(ip, W, 4 * wid, l15, g, acc);
      epiN<4>(acc, bias, 4 * wid, op, l15, g);
    }
    {
      f32x4 acc[2][3] = {};
      gemmN<NKS, 3>(ip, W, 14 + 3 * wid, l15, g, acc);
      epiN<3>(acc, bias, 14 + 3 * wid, op, l15, g);
    }
  } else {
    {
      f32x4 acc[2][3] = {};
      gemmN<NKS, 3>(ip, W, 8 + 3 * (wid - 2), l15, g, acc);
      epiN<3>(acc, bias, 8 + 3 * (wid - 2), op, l15, g);
    }
    {
      f32x4 acc[2][3] = {};
      gemmN<NKS, 3>(ip, W, 20 + 3 * (wid - 2), l15, g, acc);
      epiN<3>(acc, bias, 20 + 3 * (wid - 2), op, l15, g);
    }
  }
}

// ---- L6 chunk: gemm + tanh + y-store + fused partial A/B/M ----
template <int NFW>
__device__ __forceinline__ void l6N(const char* ip, const u16* __restrict__ W6,
                                    const float* __restrict__ bd3,
                                    const float* __restrict__ dvec,
                                    const float* __restrict__ xin,
                                    float* __restrict__ y_out,
                                    size_t row0, int nb0, int l15, int g,
                                    float (&pA)[2][4], float (&pB)[2][4], float (&pM)[2][4]) {
  f32x4 acc[2][NFW] = {};
  gemmN<13, NFW>(ip, W6, nb0, l15, g, acc);
#pragma unroll
  for (int mf = 0; mf < 2; ++mf) {
#pragma unroll
    for (int j = 0; j < 4; ++j) {
      const size_t grow = row0 + mf * 16 + g * 4 + j;
#pragma unroll
      for (int nf = 0; nf < NFW; ++nf) {
        const int col = (nb0 + nf) * 16 + l15;
        const float v = acc[mf][nf][j] + bd3[col];
        const float e = __expf(2.f * v);
        const float y = 1.f - 2.f * __builtin_amdgcn_rcpf(e + 1.f);
        y_out[grow * DDIM + col] = y;
        pA[mf][j] = fmaf(y, dvec[col], pA[mf][j]);
        pB[mf][j] = fmaf(y, y, pB[mf][j]);
        const float df = y - xin[grow * DDIM + col];
        pM[mf][j] = fmaf(df, df, pM[mf][j]);
      }
    }
  }
}

// ---------------- main fused kernel: 32 rows per block, 256 threads ----------------
// Ping-pong planes; L3/L4 are MFMA too (z as a K=32 A-fragment in the plane).
__global__ __launch_bounds__(256, 3) void k_main(
    const float* __restrict__ xin, const float* __restrict__ dvec,
    const float* __restrict__ be1, const float* __restrict__ be2, const float* __restrict__ be3,
    const float* __restrict__ bd1, const float* __restrict__ bd2, const float* __restrict__ bd3,
    const u16* __restrict__ W1, const u16* __restrict__ W2,
    const u16* __restrict__ W5, const u16* __restrict__ W6,
    const u16* __restrict__ W3, const u16* __restrict__ W4,
    const float* __restrict__ Cptr,
    float* __restrict__ y_out, float* __restrict__ z_out,
    float* __restrict__ defen, float* __restrict__ msep) {
  extern __shared__ __align__(16) char lds[];
  char* pa = lds;              // plane A
  char* pb = lds + PLANE;      // plane B

  const int tid = threadIdx.x;
  const int lane = tid & 63;
  const int wid = tid >> 6;       // 0..3
  const int l15 = lane & 15;
  const int g = lane >> 4;        // 0..3
  const size_t row0 = (size_t)blockIdx.x * ROWS;

  // ---- stage x -> plane A (f16, XOR-swz units) ----
#pragma unroll
  for (int i = 0; i < 7; ++i) {
    const int f = i * 256 + tid;                 // 32 rows * 56 float4 = 1792
    const int r = f / 56, c4 = f - r * 56;
    const float4 v = *(const float4*)(xin + (row0 + r) * DDIM + c4 * 4);
    const float vv[4] = {v.x, v.y, v.z, v.w};
    ushort4 hh;
    u16* hw = (u16*)&hh;
#pragma unroll
    for (int w = 0; w < 4; ++w) hw[w] = f2h(vv[w]);
    *(ushort4*)(pa + r * PROW + (((c4 >> 1) ^ (r & 3)) << 4) + (c4 & 1) * 8) = hh;
  }
  __syncthreads();

  // ---- L1: x(A) -> h1(B) ----
  layerN<7>(pa, pb, W1, be1, wid, l15, g);
  __syncthreads();

  // ---- L2: h1(B) -> h2(A) ----
  layerN<13>(pb, pa, W2, be2, wid, l15, g);
  __syncthreads();

  // ---- L3 (MFMA): z = h2(A) @ We3 + be3; wave 0 only ----
  // Output z scattered into plane B as a ready A-fragment (K=32, k<4 real).
  if (wid == 0) {
    f32x4 acc3[2][1] = {};
    gemmN<13, 1>(pa, W3, 0, l15, g, acc3);
    float zv[2][4];
#pragma unroll
    for (int mf = 0; mf < 2; ++mf) {
#pragma unroll
      for (int j = 0; j < 4; ++j) {
        const float s = acc3[mf][0][j] + ((l15 < 4) ? be3[l15] : 0.f);
        zv[mf][j] = s;
        if (l15 < 4) z_out[(row0 + mf * 16 + g * 4 + j) * 4 + l15] = s;
      }
    }
    // pack z (k=0..3) into unit 0; zero units 1..3 (k=8..31) of each row
#pragma unroll
    for (int mf = 0; mf < 2; ++mf) {
#pragma unroll
      for (int j = 0; j < 4; ++j) {
        const float z0 = __shfl(zv[mf][j], (lane & ~15) + 0);
        const float z1 = __shfl(zv[mf][j], (lane & ~15) + 1);
        const float z2 = __shfl(zv[mf][j], (lane & ~15) + 2);
        const float z3 = __shfl(zv[mf][j], (lane & ~15) + 3);
        if (l15 < 4) {
          const int r = mf * 16 + g * 4 + j;
          uint4 zq = {0u, 0u, 0u, 0u};
          if (l15 == 0) {
            zq.x = (u32)f2h(z0) | ((u32)f2h(z1) << 16);
            zq.y = (u32)f2h(z2) | ((u32)f2h(z3) << 16);
          }
          *(uint4*)(pb + r * PROW + ((l15 ^ (r & 3)) << 4)) = zq;
        }
      }
    }
  }
  __syncthreads();

  // ---- L4 (MFMA): g1 = lrelu(z(B) @ Wd1 + bd1) -> plane A ----
  layerN<1>(pb, pa, W4, bd1, wid, l15, g);
  __syncthreads();

  // ---- L5: g2 = lrelu(g1(A) @ Wd2 + bd2) -> plane B ----
  layerN<13>(pa, pb, W5, bd2, wid, l15, g);
  __syncthreads();                 // A now free (red overlay), B holds g2

  // ---- L6: y = tanh(g2(B) @ Wd3 + bd3) + fused reductions ----
  // 14 nb balanced {4,4,3,3}: w0:0 w1:4 w2:8 w3:11.
  {
    float pA[2][4] = {}, pB[2][4] = {}, pM[2][4] = {};
    if (wid < 2) l6N<4>(pb, W6, bd3, dvec, xin, y_out, row0, 4 * wid, l15, g, pA, pB, pM);
    else         l6N<3>(pb, W6, bd3, dvec, xin, y_out, row0, 8 + 3 * (wid - 2), l15, g, pA, pB, pM);
    float* red = (float*)pa;       // [32 rows][4 waves][4]
#pragma unroll
    for (int mf = 0; mf < 2; ++mf) {
#pragma unroll
      for (int j = 0; j < 4; ++j) {
        float a = pA[mf][j], b = pB[mf][j], m = pM[mf][j];
#pragma unroll
        for (int off = 1; off < 16; off <<= 1) {
          a += __shfl_xor(a, off);
          b += __shfl_xor(b, off);
          m += __shfl_xor(m, off);
        }
        if (l15 == 0) {
          const int lrow = mf * 16 + g * 4 + j;
          red[(lrow * 4 + wid) * 4 + 0] = a;
          red[(lrow * 4 + wid) * 4 + 1] = b;
          red[(lrow * 4 + wid) * 4 + 2] = m;
        }
      }
    }
  }
  __syncthreads();

  if (tid < 32) {
    const float Cn = Cptr[0];
    const float* red = (const float*)pa;
    float A = 0.f, B2 = 0.f, M = 0.f;
#pragma unroll
    for (int w = 0; w < 4; ++w) {
      A  += red[(tid * 4 + w) * 4 + 0];
      B2 += red[(tid * 4 + w) * 4 + 1];
      M  += red[(tid * 4 + w) * 4 + 2];
    }
    defen[row0 + tid] = A / (sqrtf(B2) * Cn + 1e-5f);
#pragma unroll
    for (int off = 1; off < 32; off <<= 1) M += __shfl_xor(M, off);
    if (tid == 0) msep[blockIdx.x] = M;
  }
}

// ---------------- top-k stage A: 64 blocks, per-block top-20 of 2048 ----------------
__global__ void k_topk_a(const float* __restrict__ defen, float* __restrict__ cand) {
  __shared__ float vals[2048];
  __shared__ float wv[4];
  __shared__ int wi[4];
  const int tid = threadIdx.x;
  const int base = blockIdx.x * 2048;
  for (int i = tid; i < 2048; i += 256) vals[i] = defen[base + i];
  __syncthreads();
  for (int it = 0; it < 20; ++it) {
    float mv = -1e30f; int mi = 1 << 30;
    for (int i = tid; i < 2048; i += 256) {
      float v = vals[i];
      if (v > mv) { mv = v; mi = i; }
    }
#pragma unroll
    for (int off = 1; off < 64; off <<= 1) {
      float ov = __shfl_xor(mv, off); int oi = __shfl_xor(mi, off);
      if (ov > mv || (ov == mv && oi < mi)) { mv = ov; mi = oi; }
    }
    if ((tid & 63) == 0) { wv[tid >> 6] = mv; wi[tid >> 6] = mi; }
    __syncthreads();
    if (tid == 0) {
      float bv = wv[0]; int bi = wi[0];
      for (int q = 1; q < 4; ++q)
        if (wv[q] > bv || (wv[q] == bv && wi[q] < bi)) { bv = wv[q]; bi = wi[q]; }
      cand[blockIdx.x * 20 + it] = bv;
      vals[bi] = -1e30f;
    }
    __syncthreads();
  }
}

// ---------------- top-k stage B: final top-20 of 1280 + R_loss ----------------
__global__ void k_topk_b(const float* __restrict__ cand, const float* __restrict__ msep,
                         float* __restrict__ rloss) {
  __shared__ float vals[1280];
  __shared__ float wv[4];
  __shared__ int wi[4];
  __shared__ float msum[4];
  const int tid = threadIdx.x;
  for (int i = tid; i < 1280; i += 256) vals[i] = cand[i];
  float ms = 0.f;
  for (int i = tid; i < 4096; i += 256) ms += msep[i];
#pragma unroll
  for (int off = 1; off < 64; off <<= 1) ms += __shfl_xor(ms, off);
  if ((tid & 63) == 0) msum[tid >> 6] = ms;
  __syncthreads();
  float sam = 0.f;
  for (int it = 0; it < 20; ++it) {
    float mv = -1e30f; int mi = 1 << 30;
    for (int i = tid; i < 1280; i += 256) {
      float v = vals[i];
      if (v > mv) { mv = v; mi = i; }
    }
#pragma unroll
    for (int off = 1; off < 64; off <<= 1) {
      float ov = __shfl_xor(mv, off); int oi = __shfl_xor(mi, off);
      if (ov > mv || (ov == mv && oi < mi)) { mv = ov; mi = oi; }
    }
    if ((tid & 63) == 0) { wv[tid >> 6] = mv; wi[tid >> 6] = mi; }
    __syncthreads();
    if (tid == 0) {
      float bv = wv[0]; int bi = wi[0];
      for (int q = 1; q < 4; ++q)
        if (wv[q] > bv || (wv[q] == bv && wi[q] < bi)) { bv = wv[q]; bi = wi[q]; }
      sam += bv;
      vals[bi] = -1e30f;
    }
    __syncthreads();
  }
  if (tid == 0) {
    float mse = (msum[0] + msum[1] + msum[2] + msum[3]) / 29360128.f;  // N*D
    rloss[0] = mse + 0.1f * sam;
  }
}

extern "C" void kernel_launch(void* const* d_in, const int* in_sizes, int n_in,
                              void* d_out, int out_size, void* d_ws, size_t ws_size,
                              hipStream_t stream) {
  const float* x    = (const float*)d_in[0];
  const float* dinp = (const float*)d_in[1];
  const float* We1  = (const float*)d_in[2];
  const float* be1  = (const float*)d_in[3];
  const float* We2  = (const float*)d_in[4];
  const float* be2  = (const float*)d_in[5];
  const float* We3  = (const float*)d_in[6];
  const float* be3  = (const float*)d_in[7];
  const float* Wd1  = (const float*)d_in[8];
  const float* bd1  = (const float*)d_in[9];
  const float* Wd2  = (const float*)d_in[10];
  const float* bd2  = (const float*)d_in[11];
  const float* Wd3  = (const float*)d_in[12];
  const float* bd3  = (const float*)d_in[13];

  float* y_out = (float*)d_out;
  float* z_out = y_out + (size_t)NROWS * DDIM;
  float* r_out = z_out + (size_t)NROWS * 4;

  char* ws = (char*)d_ws;
  u16* W1 = (u16*)(ws + OFF_W1);
  u16* W2 = (u16*)(ws + OFF_W2);
  u16* W5 = (u16*)(ws + OFF_W5);
  u16* W6 = (u16*)(ws + OFF_W6);
  u16* W3 = (u16*)(ws + OFF_W3);
  u16* W4 = (u16*)(ws + OFF_W4);
  float* Cf    = (float*)(ws + OFF_C);
  float* msep  = (float*)(ws + OFF_MSEP);
  float* defen = (float*)(ws + OFF_DEFEN);
  float* cand  = (float*)(ws + OFF_CAND);

  (void)hipFuncSetAttribute((const void*)k_main, hipFuncAttributeMaxDynamicSharedMemorySize, LDS_TOTAL);

  k_prep<<<dim3(256), dim3(256), 0, stream>>>(We1, We2, Wd2, Wd3, We3, Wd1, dinp,
                                              W1, W2, W5, W6, W3, W4, Cf);
  k_main<<<dim3(4096), dim3(256), LDS_TOTAL, stream>>>(x, dinp, be1, be2, be3, bd1, bd2, bd3,
                                                       W1, W2, W5, W6, W3, W4,
                                                       Cf, y_out, z_out, defen, msep);
  k_topk_a<<<dim3(64), dim3(256), 0, stream>>>(defen, cand);
  k_topk_b<<<dim3(1), dim3(256), 0, stream>>>(cand, msep, r_out);
}

// Round 28
// 277.351 us; speedup vs baseline: 1.1978x; 1.0006x over previous
//
#include <hip/hip_runtime.h>
#include <hip/hip_bf16.h>
#include <math.h>

typedef _Float16 f16x8 __attribute__((ext_vector_type(8)));
typedef float f32x4 __attribute__((ext_vector_type(4)));
typedef unsigned int u32;
typedef unsigned short u16;

#define NROWS 131072
#define DDIM 224
#define HREAL 400
#define HP 416          // padded hidden dim (13*32)
#define ROWS 32         // rows per block
#define PROW 832        // 52 units of 16B; XOR-unit swizzle (unit ^ (row&3))
#define PLANE 26624     // one plane: 32 * 832
#define LDS_TOTAL 53248 // plane A + plane B; 3 blocks/CU

// ---- workspace layout (bytes); weights single-f16 fragment-linear ----
#define OFF_W1    0          // [26nb][7ks][4g][16l][8] u16 = 186368 B
#define OFF_W2    186368     // [26][13][4][16][8] = 346112 B
#define OFF_W5    532480     // 346112 B
#define OFF_W6    878592     // [14][13][4][16][8] = 186368 B
#define OFF_W3    1064960    // [1][13][4][16][8] = 13312 B  (We3 as B-frag, N=16 cols<4 real)
#define OFF_W4    1078272    // [26][1][4][16][8] = 26624 B  (Wd1 as B-frag, K=32 k<4 real)
#define OFF_C     1104896    // f32 scalar ||d||
#define OFF_MSEP  1104912    // f32 [4096]
#define OFF_DEFEN 1121296    // f32 [131072]
#define OFF_CAND  1645584    // f32 [1280]
// total 1650704 bytes

__device__ __forceinline__ u16 f2h(float v) {
  union { _Float16 h; u16 u; } c;
  c.h = (_Float16)v;
  return c.u;
}

// single-f16 fragment packing: u16 index i -> (nb, ks, g, l15, e)
__device__ __forceinline__ void pack8(int i, int NKS, int KREAL, int NREAL, int NLD,
                                      const float* __restrict__ W,
                                      u16* __restrict__ Wo) {
  const int e = i & 7, l15 = (i >> 3) & 15, g = (i >> 7) & 3;
  const int rest = i >> 9;
  const int ks = rest % NKS, nb = rest / NKS;
  const int n = nb * 16 + l15, k = ks * 32 + g * 8 + e;
  const float w = (n < NREAL && k < KREAL) ? W[k * NLD + n] : 0.f;
  Wo[i] = f2h(w);
}

__global__ void k_prep(const float* __restrict__ We1, const float* __restrict__ We2,
                       const float* __restrict__ Wd2, const float* __restrict__ Wd3,
                       const float* __restrict__ We3, const float* __restrict__ Wd1,
                       const float* __restrict__ dvec,
                       u16* __restrict__ W1, u16* __restrict__ W2,
                       u16* __restrict__ W5, u16* __restrict__ W6,
                       u16* __restrict__ W3, u16* __restrict__ W4,
                       float* __restrict__ Cout) {
  const int t = blockIdx.x * 256 + threadIdx.x;
  const int NT = gridDim.x * 256;
  for (int i = t; i < 26 * 7 * 512;  i += NT) pack8(i, 7,  DDIM,  HREAL, HREAL, We1, W1);
  for (int i = t; i < 26 * 13 * 512; i += NT) pack8(i, 13, HREAL, HREAL, HREAL, We2, W2);
  for (int i = t; i < 26 * 13 * 512; i += NT) pack8(i, 13, HREAL, HREAL, HREAL, Wd2, W5);
  for (int i = t; i < 14 * 13 * 512; i += NT) pack8(i, 13, HREAL, DDIM,  DDIM,  Wd3, W6);
  for (int i = t; i < 1 * 13 * 512;  i += NT) pack8(i, 13, HREAL, 4,     4,     We3, W3);
  for (int i = t; i < 26 * 1 * 512;  i += NT) pack8(i, 1,  4,     HREAL, HREAL, Wd1, W4);
  if (blockIdx.x == 0) {
    float s = 0.f;
    for (int i = threadIdx.x; i < DDIM; i += 256) { float v = dvec[i]; s += v * v; }
#pragma unroll
    for (int off = 1; off < 64; off <<= 1) s += __shfl_xor(s, off);
    __shared__ float cs[4];
    if ((threadIdx.x & 63) == 0) cs[threadIdx.x >> 6] = s;
    __syncthreads();
    if (threadIdx.x == 0) Cout[0] = sqrtf(cs[0] + cs[1] + cs[2] + cs[3]);
  }
}

// ------- GEMM chunk: 2 M-frags x NFW N-frags, f16 single-W, depth-1 prefetch -------
// XOR-unit swizzle folds into the per-thread base; k-loop A addresses are
// compile-time offsets (zero per-k-step address VALU).
template <int NKS, int NFW>
__device__ __forceinline__ void gemmN(const char* ip, const u16* __restrict__ W,
                                      int nb0, int l15, int g, f32x4 (&acc)[2][NFW]) {
  const int lof = (g << 7) + (l15 << 3);
  const int gs = g ^ (l15 & 3);                 // swizzled unit low bits
  const char* a0b = ip + l15 * PROW + gs * 16;
  const char* a1b = a0b + 16 * PROW;            // (l15+16)&3 == l15&3 -> same gs
  const u16* wp[NFW];
#pragma unroll
  for (int nf = 0; nf < NFW; ++nf)
    wp[nf] = W + ((((size_t)(nb0 + nf) * NKS) << 9) + lof);
  f16x8 bc[NFW];
#pragma unroll
  for (int nf = 0; nf < NFW; ++nf) bc[nf] = *(const f16x8*)wp[nf];
#pragma unroll
  for (int ks = 0; ks < NKS; ++ks) {
    f16x8 bn[NFW];
    if (ks + 1 < NKS) {
#pragma unroll
      for (int nf = 0; nf < NFW; ++nf)
        bn[nf] = *(const f16x8*)(wp[nf] + (size_t)(ks + 1) * 512);
    }
    const f16x8 a0 = *(const f16x8*)(a0b + ks * 64);
    const f16x8 a1 = *(const f16x8*)(a1b + ks * 64);
    __builtin_amdgcn_s_setprio(1);
#pragma unroll
    for (int nf = 0; nf < NFW; ++nf) {
      acc[0][nf] = __builtin_amdgcn_mfma_f32_16x16x32_f16(a0, bc[nf], acc[0][nf], 0, 0, 0);
      acc[1][nf] = __builtin_amdgcn_mfma_f32_16x16x32_f16(a1, bc[nf], acc[1][nf], 0, 0, 0);
    }
    __builtin_amdgcn_s_setprio(0);
    if (ks + 1 < NKS) {
#pragma unroll
      for (int nf = 0; nf < NFW; ++nf) bc[nf] = bn[nf];
    }
  }
}

// ---------------- activation epilogue: bias + lrelu -> OUT plane (f16, XOR-swz) -----
template <int NFW>
__device__ __forceinline__ void epiN(f32x4 (&acc)[2][NFW], const float* __restrict__ bias,
                                     int nb0, char* op, int l15, int g) {
#pragma unroll
  for (int nf = 0; nf < NFW; ++nf) {
    const int col = (nb0 + nf) * 16 + l15;
    const float bv = (col < HREAL) ? bias[col] : 0.f;
    const int cu = col >> 3;            // 16B unit
    const int crem = (col & 7) * 2;     // byte within unit
#pragma unroll
    for (int mf = 0; mf < 2; ++mf) {
#pragma unroll
      for (int j = 0; j < 4; ++j) {
        const int row = mf * 16 + g * 4 + j;
        float v = acc[mf][nf][j] + bv;
        v = fmaxf(v, 0.1f * v);
        *(u16*)(op + row * PROW + ((cu ^ (row & 3)) << 4) + crem) = f2h(v);
      }
    }
  }
}

// ---- one hidden layer: balanced wave split {7,7,6,6} of 26 nb ----
// w0: [0,4)+[14,17)  w1: [4,8)+[17,20)  w2: [8,11)+[20,23)  w3: [11,14)+[23,26)
// Critical path 7 nb (was 8 with round-robin).
template <int NKS>
__device__ __forceinline__ void layerN(const char* ip, char* op,
                                       const u16* __restrict__ W,
                                       const float* __restrict__ bias,
                                       int wid, int l15, int g) {
  if (wid < 2) {
    {
      f32x4 acc[2][4] = {};
      gemmN<NKS, 4>(ip, W, 4 * wid, l15, g, acc);
      epiN<4>(acc, bias, 4 * wid, op, l15, g);
    }
    {
      f32x4 acc[2][3] = {};
      gemmN<NKS, 3>(ip, W, 14 + 3 * wid, l15, g, acc);
      epiN<3>(acc, bias, 14 + 3 * wid, op, l15, g);
    }
  } else {
    {
      f32x4 acc[2][3] = {};
      gemmN<NKS, 3>(ip, W, 8 + 3 * (wid - 2), l15, g, acc);
      epiN<3>(acc, bias, 8 + 3 * (wid - 2), op, l15, g);
    }
    {
      f32x4 acc[2][3] = {};
      gemmN<NKS, 3>(ip, W, 20 + 3 * (wid - 2), l15, g, acc);
      epiN<3>(acc, bias, 20 + 3 * (wid - 2), op, l15, g);
    }
  }
}

// ---- L6 chunk: gemm + tanh + y-store + fused partial A/B/M ----
template <int NFW>
__device__ __forceinline__ void l6N(const char* ip, const u16* __restrict__ W6,
                                    const float* __restrict__ bd3,
                                    const float* __restrict__ dvec,
                                    const float* __restrict__ xin,
                                    float* __restrict__ y_out,
                                    size_t row0, int nb0, int l15, int g,
                                    float (&pA)[2][4], float (&pB)[2][4], float (&pM)[2][4]) {
  f32x4 acc[2][NFW] = {};
  gemmN<13, NFW>(ip, W6, nb0, l15, g, acc);
#pragma unroll
  for (int mf = 0; mf < 2; ++mf) {
#pragma unroll
    for (int j = 0; j < 4; ++j) {
      const size_t grow = row0 + mf * 16 + g * 4 + j;
#pragma unroll
      for (int nf = 0; nf < NFW; ++nf) {
        const int col = (nb0 + nf) * 16 + l15;
        const float v = acc[mf][nf][j] + bd3[col];
        const float e = __expf(2.f * v);
        const float y = 1.f - 2.f * __builtin_amdgcn_rcpf(e + 1.f);
        y_out[grow * DDIM + col] = y;
        pA[mf][j] = fmaf(y, dvec[col], pA[mf][j]);
        pB[mf][j] = fmaf(y, y, pB[mf][j]);
        const float df = y - xin[grow * DDIM + col];
        pM[mf][j] = fmaf(df, df, pM[mf][j]);
      }
    }
  }
}

// ---------------- main fused kernel: 32 rows per block, 256 threads ----------------
// Ping-pong planes; L3/L4 are MFMA too (z as a K=32 A-fragment in the plane).
__global__ __launch_bounds__(256, 3) void k_main(
    const float* __restrict__ xin, const float* __restrict__ dvec,
    const float* __restrict__ be1, const float* __restrict__ be2, const float* __restrict__ be3,
    const float* __restrict__ bd1, const float* __restrict__ bd2, const float* __restrict__ bd3,
    const u16* __restrict__ W1, const u16* __restrict__ W2,
    const u16* __restrict__ W5, const u16* __restrict__ W6,
    const u16* __restrict__ W3, const u16* __restrict__ W4,
    const float* __restrict__ Cptr,
    float* __restrict__ y_out, float* __restrict__ z_out,
    float* __restrict__ defen, float* __restrict__ msep) {
  extern __shared__ __align__(16) char lds[];
  char* pa = lds;              // plane A
  char* pb = lds + PLANE;      // plane B

  const int tid = threadIdx.x;
  const int lane = tid & 63;
  const int wid = tid >> 6;       // 0..3
  const int l15 = lane & 15;
  const int g = lane >> 4;        // 0..3
  const size_t row0 = (size_t)blockIdx.x * ROWS;

  // ---- stage x -> plane A (f16, XOR-swz units) ----
#pragma unroll
  for (int i = 0; i < 7; ++i) {
    const int f = i * 256 + tid;                 // 32 rows * 56 float4 = 1792
    const int r = f / 56, c4 = f - r * 56;
    const float4 v = *(const float4*)(xin + (row0 + r) * DDIM + c4 * 4);
    const float vv[4] = {v.x, v.y, v.z, v.w};
    ushort4 hh;
    u16* hw = (u16*)&hh;
#pragma unroll
    for (int w = 0; w < 4; ++w) hw[w] = f2h(vv[w]);
    *(ushort4*)(pa + r * PROW + (((c4 >> 1) ^ (r & 3)) << 4) + (c4 & 1) * 8) = hh;
  }
  __syncthreads();

  // ---- L1: x(A) -> h1(B) ----
  layerN<7>(pa, pb, W1, be1, wid, l15, g);
  __syncthreads();

  // ---- L2: h1(B) -> h2(A) ----
  layerN<13>(pb, pa, W2, be2, wid, l15, g);
  __syncthreads();

  // ---- L3 (MFMA): z = h2(A) @ We3 + be3; wave 0 only ----
  // Output z scattered into plane B as a ready A-fragment (K=32, k<4 real).
  if (wid == 0) {
    f32x4 acc3[2][1] = {};
    gemmN<13, 1>(pa, W3, 0, l15, g, acc3);
    float zv[2][4];
#pragma unroll
    for (int mf = 0; mf < 2; ++mf) {
#pragma unroll
      for (int j = 0; j < 4; ++j) {
        const float s = acc3[mf][0][j] + ((l15 < 4) ? be3[l15] : 0.f);
        zv[mf][j] = s;
        if (l15 < 4) z_out[(row0 + mf * 16 + g * 4 + j) * 4 + l15] = s;
      }
    }
    // pack z (k=0..3) into unit 0; zero units 1..3 (k=8..31) of each row
#pragma unroll
    for (int mf = 0; mf < 2; ++mf) {
#pragma unroll
      for (int j = 0; j < 4; ++j) {
        const float z0 = __shfl(zv[mf][j], (lane & ~15) + 0);
        const float z1 = __shfl(zv[mf][j], (lane & ~15) + 1);
        const float z2 = __shfl(zv[mf][j], (lane & ~15) + 2);
        const float z3 = __shfl(zv[mf][j], (lane & ~15) + 3);
        if (l15 < 4) {
          const int r = mf * 16 + g * 4 + j;
          uint4 zq = {0u, 0u, 0u, 0u};
          if (l15 == 0) {
            zq.x = (u32)f2h(z0) | ((u32)f2h(z1) << 16);
            zq.y = (u32)f2h(z2) | ((u32)f2h(z3) << 16);
          }
          *(uint4*)(pb + r * PROW + ((l15 ^ (r & 3)) << 4)) = zq;
        }
      }
    }
  }
  __syncthreads();

  // ---- L4 (MFMA): g1 = lrelu(z(B) @ Wd1 + bd1) -> plane A ----
  layerN<1>(pb, pa, W4, bd1, wid, l15, g);
  __syncthreads();

  // ---- L5: g2 = lrelu(g1(A) @ Wd2 + bd2) -> plane B ----
  layerN<13>(pa, pb, W5, bd2, wid, l15, g);
  __syncthreads();                 // A now free (red overlay), B holds g2

  // ---- L6: y = tanh(g2(B) @ Wd3 + bd3) + fused reductions ----
  // 14 nb balanced {4,4,3,3}: w0:0 w1:4 w2:8 w3:11.
  {
    float pA[2][4] = {}, pB[2][4] = {}, pM[2][4] = {};
    if (wid < 2) l6N<4>(pb, W6, bd3, dvec, xin, y_out, row0, 4 * wid, l15, g, pA, pB, pM);
    else         l6N<3>(pb, W6, bd3, dvec, xin, y_out, row0, 8 + 3 * (wid - 2), l15, g, pA, pB, pM);
    float* red = (float*)pa;       // [32 rows][4 waves][4]
#pragma unroll
    for (int mf = 0; mf < 2; ++mf) {
#pragma unroll
      for (int j = 0; j < 4; ++j) {
        float a = pA[mf][j], b = pB[mf][j], m = pM[mf][j];
#pragma unroll
        for (int off = 1; off < 16; off <<= 1) {
          a += __shfl_xor(a, off);
          b += __shfl_xor(b, off);
          m += __shfl_xor(m, off);
        }
        if (l15 == 0) {
          const int lrow = mf * 16 + g * 4 + j;
          red[(lrow * 4 + wid) * 4 + 0] = a;
          red[(lrow * 4 + wid) * 4 + 1] = b;
          red[(lrow * 4 + wid) * 4 + 2] = m;
        }
      }
    }
  }
  __syncthreads();

  if (tid < 32) {
    const float Cn = Cptr[0];
    const float* red = (const float*)pa;
    float A = 0.f, B2 = 0.f, M = 0.f;
#pragma unroll
    for (int w = 0; w < 4; ++w) {
      A  += red[(tid * 4 + w) * 4 + 0];
      B2 += red[(tid * 4 + w) * 4 + 1];
      M  += red[(tid * 4 + w) * 4 + 2];
    }
    defen[row0 + tid] = A / (sqrtf(B2) * Cn + 1e-5f);
#pragma unroll
    for (int off = 1; off < 32; off <<= 1) M += __shfl_xor(M, off);
    if (tid == 0) msep[blockIdx.x] = M;
  }
}

// ---------------- top-k stage A: 64 blocks, per-block top-20 of 2048 ----------------
__global__ void k_topk_a(const float* __restrict__ defen, float* __restrict__ cand) {
  __shared__ float vals[2048];
  __shared__ float wv[4];
  __shared__ int wi[4];
  const int tid = threadIdx.x;
  const int base = blockIdx.x * 2048;
  for (int i = tid; i < 2048; i += 256) vals[i] = defen[base + i];
  __syncthreads();
  for (int it = 0; it < 20; ++it) {
    float mv = -1e30f; int mi = 1 << 30;
    for (int i = tid; i < 2048; i += 256) {
      float v = vals[i];
      if (v > mv) { mv = v; mi = i; }
    }
#pragma unroll
    for (int off = 1; off < 64; off <<= 1) {
      float ov = __shfl_xor(mv, off); int oi = __shfl_xor(mi, off);
      if (ov > mv || (ov == mv && oi < mi)) { mv = ov; mi = oi; }
    }
    if ((tid & 63) == 0) { wv[tid >> 6] = mv; wi[tid >> 6] = mi; }
    __syncthreads();
    if (tid == 0) {
      float bv = wv[0]; int bi = wi[0];
      for (int q = 1; q < 4; ++q)
        if (wv[q] > bv || (wv[q] == bv && wi[q] < bi)) { bv = wv[q]; bi = wi[q]; }
      cand[blockIdx.x * 20 + it] = bv;
      vals[bi] = -1e30f;
    }
    __syncthreads();
  }
}

// ---------------- top-k stage B: final top-20 of 1280 + R_loss ----------------
__global__ void k_topk_b(const float* __restrict__ cand, const float* __restrict__ msep,
                         float* __restrict__ rloss) {
  __shared__ float vals[1280];
  __shared__ float wv[4];
  __shared__ int wi[4];
  __shared__ float msum[4];
  const int tid = threadIdx.x;
  for (int i = tid; i < 1280; i += 256) vals[i] = cand[i];
  float ms = 0.f;
  for (int i = tid; i < 4096; i += 256) ms += msep[i];
#pragma unroll
  for (int off = 1; off < 64; off <<= 1) ms += __shfl_xor(ms, off);
  if ((tid & 63) == 0) msum[tid >> 6] = ms;
  __syncthreads();
  float sam = 0.f;
  for (int it = 0; it < 20; ++it) {
    float mv = -1e30f; int mi = 1 << 30;
    for (int i = tid; i < 1280; i += 256) {
      float v = vals[i];
      if (v > mv) { mv = v; mi = i; }
    }
#pragma unroll
    for (int off = 1; off < 64; off <<= 1) {
      float ov = __shfl_xor(mv, off); int oi = __shfl_xor(mi, off);
      if (ov > mv || (ov == mv && oi < mi)) { mv = ov; mi = oi; }
    }
    if ((tid & 63) == 0) { wv[tid >> 6] = mv; wi[tid >> 6] = mi; }
    __syncthreads();
    if (tid == 0) {
      float bv = wv[0]; int bi = wi[0];
      for (int q = 1; q < 4; ++q)
        if (wv[q] > bv || (wv[q] == bv && wi[q] < bi)) { bv = wv[q]; bi = wi[q]; }
      sam += bv;
      vals[bi] = -1e30f;
    }
    __syncthreads();
  }
  if (tid == 0) {
    float mse = (msum[0] + msum[1] + msum[2] + msum[3]) / 29360128.f;  // N*D
    rloss[0] = mse + 0.1f * sam;
  }
}

extern "C" void kernel_launch(void* const* d_in, const int* in_sizes, int n_in,
                              void* d_out, int out_size, void* d_ws, size_t ws_size,
                              hipStream_t stream) {
  const float* x    = (const float*)d_in[0];
  const float* dinp = (const float*)d_in[1];
  const float* We1  = (const float*)d_in[2];
  const float* be1  = (const float*)d_in[3];
  const float* We2  = (const float*)d_in[4];
  const float* be2  = (const float*)d_in[5];
  const float* We3  = (const float*)d_in[6];
  const float* be3  = (const float*)d_in[7];
  const float* Wd1  = (const float*)d_in[8];
  const float* bd1  = (const float*)d_in[9];
  const float* Wd2  = (const float*)d_in[10];
  const float* bd2  = (const float*)d_in[11];
  const float* Wd3  = (const float*)d_in[12];
  const float* bd3  = (const float*)d_in[13];

  float* y_out = (float*)d_out;
  float* z_out = y_out + (size_t)NROWS * DDIM;
  float* r_out = z_out + (size_t)NROWS * 4;

  char* ws = (char*)d_ws;
  u16* W1 = (u16*)(ws + OFF_W1);
  u16* W2 = (u16*)(ws + OFF_W2);
  u16* W5 = (u16*)(ws + OFF_W5);
  u16* W6 = (u16*)(ws + OFF_W6);
  u16* W3 = (u16*)(ws + OFF_W3);
  u16* W4 = (u16*)(ws + OFF_W4);
  float* Cf    = (float*)(ws + OFF_C);
  float* msep  = (float*)(ws + OFF_MSEP);
  float* defen = (float*)(ws + OFF_DEFEN);
  float* cand  = (float*)(ws + OFF_CAND);

  (void)hipFuncSetAttribute((const void*)k_main, hipFuncAttributeMaxDynamicSharedMemorySize, LDS_TOTAL);

  k_prep<<<dim3(256), dim3(256), 0, stream>>>(We1, We2, Wd2, Wd3, We3, Wd1, dinp,
                                              W1, W2, W5, W6, W3, W4, Cf);
  k_main<<<dim3(4096), dim3(256), LDS_TOTAL, stream>>>(x, dinp, be1, be2, be3, bd1, bd2, bd3,
                                                       W1, W2, W5, W6, W3, W4,
                                                       Cf, y_out, z_out, defen, msep);
  k_topk_a<<<dim3(64), dim3(256), 0, stream>>>(defen, cand);
  k_topk_b<<<dim3(1), dim3(256), 0, stream>>>(cand, msep, r_out);
}